// Round 3
// baseline (81.510 us; speedup 1.0000x reference)
//
#include <hip/hip_runtime.h>

#define T_STEPS 256
#define B_SIZE  128
#define N_TAGS  64
#define START_IDX 1
#define END_IDX 2

typedef float  f32x4  __attribute__((ext_vector_type(4)));
typedef short  bf16x8 __attribute__((ext_vector_type(8)));

union U8 { unsigned u[4]; bf16x8 v; };

__device__ __forceinline__ float fexp2(float x){float r;asm("v_exp_f32 %0, %1":"=v"(r):"v"(x));return r;}
__device__ __forceinline__ float flog2(float x){float r;asm("v_log_f32 %0, %1":"=v"(r):"v"(x));return r;}
__device__ __forceinline__ float frcp(float x){float r;asm("v_rcp_f32 %0, %1":"=v"(r):"v"(x));return r;}
__device__ __forceinline__ unsigned cvtpk(float lo,float hi){unsigned r;asm("v_cvt_pk_bf16_f32 %0, %1, %2":"=v"(r):"v"(lo),"v"(hi));return r;}
// CDNA4: swap A.hi32lanes <-> B.lo32lanes  /  A.odd16rows <-> B.even16rows
__device__ __forceinline__ void swap32(unsigned &a, unsigned &b){asm("v_permlane32_swap_b32 %0, %1":"+v"(a),"+v"(b));}
__device__ __forceinline__ void swap16(unsigned &a, unsigned &b){asm("v_permlane16_swap_b32 %0, %1":"+v"(a),"+v"(b));}

__launch_bounds__(64, 1)
__global__ void crf_mfma_kernel(const float* __restrict__ unary,
                                const float* __restrict__ trans,
                                const int* __restrict__ lengths,
                                float* __restrict__ out) {
    const int lane = threadIdx.x;
    const int col  = lane & 15;          // batch within wave (MFMA col)
    const int g    = lane >> 4;          // lane group
    const int bidx = blockIdx.x * 16 + col;

    __shared__ __align__(16) float sT[N_TAGS * N_TAGS];
    {
        const float4* t4 = (const float4*)trans;
        float4* s4 = (float4*)sT;
#pragma unroll
        for (int k = 0; k < 16; ++k) s4[k*64 + lane] = t4[k*64 + lane];
    }
    __syncthreads();

    const float K   = 1.4426950408889634f;   // log2(e)
    const float LN2 = 0.6931471805599453f;
    const f32x4 zf = {0.f, 0.f, 0.f, 0.f};

    // A-operand fragments of E = exp(trans): EA[tile][chunk]
    // lane holds A[row=col][k=8g+j] -> E[16*tile+col][32*chunk+8g+j]
    U8 EA[4][2];
#pragma unroll
    for (int tt = 0; tt < 4; ++tt)
#pragma unroll
        for (int c = 0; c < 2; ++c) {
            const float* p = &sT[(16*tt + col)*64 + 32*c + 8*g];
#pragma unroll
            for (int j2 = 0; j2 < 4; ++j2)
                EA[tt][c].u[j2] = cvtpk(fexp2(p[2*j2]*K), fexp2(p[2*j2+1]*K));
        }
    // Terminal A fragment: all rows = exp(trans[END][fr=k])
    U8 AE[2];
#pragma unroll
    for (int c = 0; c < 2; ++c) {
        const float* p = &sT[END_IDX*64 + 32*c + 8*g];
#pragma unroll
        for (int j2 = 0; j2 < 4; ++j2)
            AE[c].u[j2] = cvtpk(fexp2(p[2*j2]*K), fexp2(p[2*j2+1]*K));
    }

    // D preset for step 0: dot[to] := exp(trans[to][START]) so that
    // w0 = dot * exp(u0) = exp(u0 + tStart).  D layout: row = 16*tt + 4g + r.
    f32x4 D[4];
#pragma unroll
    for (int tt = 0; tt < 4; ++tt)
#pragma unroll
        for (int r = 0; r < 4; ++r)
            D[tt][r] = fexp2(sT[(16*tt + 4*g + r)*64 + START_IDX] * K);

    const int len = lengths[bidx];
    int tmx = len;
#pragma unroll
    for (int m = 1; m < 64; m <<= 1) tmx = max(tmx, __shfl_xor(tmx, m, 64));
    tmx = __builtin_amdgcn_readfirstlane(tmx);
    const int loopn = (tmx + 3) & ~3;    // multiple of 4; extra steps harmless

    // u ring: element offset for (t, b=bidx, to=16*tt+4g+r); +16*tt via imm.
    unsigned uo = (unsigned)bidx * 64u + 4u * (unsigned)g;
#define LOADU(UB, OFF) do { \
        UB[0] = *(const f32x4*)(unary + (OFF)); \
        UB[1] = *(const f32x4*)(unary + (OFF) + 16); \
        UB[2] = *(const f32x4*)(unary + (OFF) + 32); \
        UB[3] = *(const f32x4*)(unary + (OFF) + 48); \
    } while (0)

    f32x4 U0[4], U1[4], U2[4], U3[4];
    LOADU(U0, uo);
    LOADU(U1, uo + 8192u);
    LOADU(U2, uo + 16384u);
    LOADU(U3, uo + 24576u);
    unsigned uo4 = uo + 32768u;   // next load position (t = 4)
    int nt = 4;

    float C = 0.0f, snapC = 0.0f;
    unsigned snap0=0,snap1=0,snap2=0,snap3=0,snap4=0,snap5=0,snap6=0,snap7=0;

#define STEP(QQ, UB) do { \
        const int t_ = s + (QQ); \
        float w_[4][4]; \
        _Pragma("unroll") \
        for (int tt = 0; tt < 4; ++tt) { \
            _Pragma("unroll") \
            for (int r = 0; r < 4; ++r) \
                w_[tt][r] = D[tt][r] * fexp2(UB[tt][r] * K); \
        } \
        if (((t_) & 7) == 7) { \
            float m0 = fmaxf(fmaxf(w_[0][0], w_[0][1]), fmaxf(w_[0][2], w_[0][3])); \
            float m1 = fmaxf(fmaxf(w_[1][0], w_[1][1]), fmaxf(w_[1][2], w_[1][3])); \
            float m2 = fmaxf(fmaxf(w_[2][0], w_[2][1]), fmaxf(w_[2][2], w_[2][3])); \
            float m3 = fmaxf(fmaxf(w_[3][0], w_[3][1]), fmaxf(w_[3][2], w_[3][3])); \
            float mm = fmaxf(fmaxf(m0, m1), fmaxf(m2, m3)); \
            mm = fmaxf(mm, __shfl_xor(mm, 16, 64)); \
            mm = fmaxf(mm, __shfl_xor(mm, 32, 64)); \
            float inv_ = frcp(mm); \
            C += LN2 * flog2(mm); \
            _Pragma("unroll") \
            for (int tt = 0; tt < 4; ++tt) { \
                _Pragma("unroll") \
                for (int r = 0; r < 4; ++r) w_[tt][r] *= inv_; \
            } \
        } \
        unsigned p00 = cvtpk(w_[0][0], w_[0][1]), p01 = cvtpk(w_[0][2], w_[0][3]); \
        unsigned p10 = cvtpk(w_[1][0], w_[1][1]), p11 = cvtpk(w_[1][2], w_[1][3]); \
        unsigned p20 = cvtpk(w_[2][0], w_[2][1]), p21 = cvtpk(w_[2][2], w_[2][3]); \
        unsigned p30 = cvtpk(w_[3][0], w_[3][1]), p31 = cvtpk(w_[3][2], w_[3][3]); \
        swap32(p00, p10); swap32(p01, p11); swap32(p20, p30); swap32(p21, p31); \
        swap16(p00, p10); swap16(p01, p11); swap16(p20, p30); swap16(p21, p31); \
        if (__ballot(len == t_ + 1)) { \
            const bool cc = (len == t_ + 1); \
            snap0 = cc ? p00 : snap0; snap1 = cc ? p01 : snap1; \
            snap2 = cc ? p10 : snap2; snap3 = cc ? p11 : snap3; \
            snap4 = cc ? p20 : snap4; snap5 = cc ? p21 : snap5; \
            snap6 = cc ? p30 : snap6; snap7 = cc ? p31 : snap7; \
            snapC = cc ? C : snapC; \
        } \
        U8 b0_, b1_; \
        b0_.u[0] = p00; b0_.u[1] = p01; b0_.u[2] = p10; b0_.u[3] = p11; \
        b1_.u[0] = p20; b1_.u[1] = p21; b1_.u[2] = p30; b1_.u[3] = p31; \
        _Pragma("unroll") \
        for (int tt = 0; tt < 4; ++tt) { \
            f32x4 acc_ = __builtin_amdgcn_mfma_f32_16x16x32_bf16(EA[tt][0].v, b0_.v, zf, 0, 0, 0); \
            D[tt] = __builtin_amdgcn_mfma_f32_16x16x32_bf16(EA[tt][1].v, b1_.v, acc_, 0, 0, 0); \
        } \
        LOADU(UB, uo4); \
        uo4 += (nt < 255) ? 8192u : 0u; ++nt; \
    } while (0)

    for (int s = 0; s < loopn; s += 4) {
        STEP(0, U0);
        STEP(1, U1);
        STEP(2, U2);
        STEP(3, U3);
    }

    // Terminal: out[b] = snapC + ln( sum_fr exp(tEnd[fr]) * wSnap[fr][b] )
    U8 w0_, w1_;
    w0_.u[0]=snap0; w0_.u[1]=snap1; w0_.u[2]=snap2; w0_.u[3]=snap3;
    w1_.u[0]=snap4; w1_.u[1]=snap5; w1_.u[2]=snap6; w1_.u[3]=snap7;
    f32x4 acc = __builtin_amdgcn_mfma_f32_16x16x32_bf16(AE[0].v, w0_.v, zf, 0, 0, 0);
    acc = __builtin_amdgcn_mfma_f32_16x16x32_bf16(AE[1].v, w1_.v, acc, 0, 0, 0);
    if (lane < 16) out[bidx] = snapC + LN2 * flog2(acc[0]);
}

extern "C" void kernel_launch(void* const* d_in, const int* in_sizes, int n_in,
                              void* d_out, int out_size, void* d_ws, size_t ws_size,
                              hipStream_t stream) {
    const float* unary   = (const float*)d_in[0];
    const float* trans   = (const float*)d_in[1];
    const int*   lengths = (const int*)d_in[2];
    float* out = (float*)d_out;

    hipLaunchKernelGGL(crf_mfma_kernel, dim3(B_SIZE / 16), dim3(64), 0, stream,
                       unary, trans, lengths, out);
}

// Round 4
// 68.688 us; speedup vs baseline: 1.1867x; 1.1867x over previous
//
#include <hip/hip_runtime.h>

#define T_STEPS 256
#define B_SIZE  128
#define N_TAGS  64
#define START_IDX 1
#define END_IDX 2

typedef float  f32x4  __attribute__((ext_vector_type(4)));
typedef short  bf16x8 __attribute__((ext_vector_type(8)));

union U8 { unsigned u[4]; bf16x8 v; };

__device__ __forceinline__ float fexp2(float x){float r;asm("v_exp_f32 %0, %1":"=v"(r):"v"(x));return r;}
__device__ __forceinline__ float flog2(float x){float r;asm("v_log_f32 %0, %1":"=v"(r):"v"(x));return r;}
__device__ __forceinline__ float frcp(float x){float r;asm("v_rcp_f32 %0, %1":"=v"(r):"v"(x));return r;}
__device__ __forceinline__ unsigned cvtpk(float lo,float hi){unsigned r;asm("v_cvt_pk_bf16_f32 %0, %1, %2":"=v"(r):"v"(lo),"v"(hi));return r;}
__device__ __forceinline__ void swap32(unsigned &a, unsigned &b){asm("v_permlane32_swap_b32 %0, %1":"+v"(a),"+v"(b));}
__device__ __forceinline__ void swap16(unsigned &a, unsigned &b){asm("v_permlane16_swap_b32 %0, %1":"+v"(a),"+v"(b));}

// Bulk: eu[i] = exp(unary[i]) = exp2(unary[i] * log2e).  2M elems, 1 float4/thread.
__global__ void expk_kernel(const float* __restrict__ u, float* __restrict__ eu) {
    const float K = 1.4426950408889634f;
    size_t i = (size_t)blockIdx.x * blockDim.x + threadIdx.x;
    f32x4 v = *(const f32x4*)(u + 4 * i);
    f32x4 r;
    r[0] = fexp2(v[0] * K); r[1] = fexp2(v[1] * K);
    r[2] = fexp2(v[2] * K); r[3] = fexp2(v[3] * K);
    *(f32x4*)(eu + 4 * i) = r;
}

// EUP=1: src holds precomputed exp(unary) -> w = D * src.
// EUP=0: src holds raw unary            -> w = D * exp2(src*K)  (fallback).
template<bool EUP>
__launch_bounds__(64, 1)
__global__ void crf_mfma_kernel(const float* __restrict__ src,
                                const float* __restrict__ trans,
                                const int* __restrict__ lengths,
                                float* __restrict__ out) {
    const int lane = threadIdx.x;
    const int col  = lane & 15;          // batch within wave (MFMA col)
    const int g    = lane >> 4;          // lane group
    const int bidx = blockIdx.x * 16 + col;

    __shared__ __align__(16) float sT[N_TAGS * N_TAGS];
    {
        const float4* t4 = (const float4*)trans;
        float4* s4 = (float4*)sT;
#pragma unroll
        for (int k = 0; k < 16; ++k) s4[k*64 + lane] = t4[k*64 + lane];
    }
    __syncthreads();

    const float K   = 1.4426950408889634f;
    const float LN2 = 0.6931471805599453f;
    const f32x4 zf = {0.f, 0.f, 0.f, 0.f};

    // A-operand fragments of E = exp(trans): lane holds A[row=col][k=8g+j].
    U8 EA[4][2];
#pragma unroll
    for (int tt = 0; tt < 4; ++tt)
#pragma unroll
        for (int c = 0; c < 2; ++c) {
            const float* p = &sT[(16*tt + col)*64 + 32*c + 8*g];
#pragma unroll
            for (int j2 = 0; j2 < 4; ++j2)
                EA[tt][c].u[j2] = cvtpk(fexp2(p[2*j2]*K), fexp2(p[2*j2+1]*K));
        }
    U8 AE[2];  // terminal: rows = exp(trans[END][fr=k])
#pragma unroll
    for (int c = 0; c < 2; ++c) {
        const float* p = &sT[END_IDX*64 + 32*c + 8*g];
#pragma unroll
        for (int j2 = 0; j2 < 4; ++j2)
            AE[c].u[j2] = cvtpk(fexp2(p[2*j2]*K), fexp2(p[2*j2+1]*K));
    }

    // D preset so step 0 gives w0 = exp(u0 + trans[to][START]).
    f32x4 D[4];
#pragma unroll
    for (int tt = 0; tt < 4; ++tt)
#pragma unroll
        for (int r = 0; r < 4; ++r)
            D[tt][r] = fexp2(sT[(16*tt + 4*g + r)*64 + START_IDX] * K);

    const int len = lengths[bidx];
    int tmx = len;
#pragma unroll
    for (int m = 1; m < 64; m <<= 1) tmx = max(tmx, __shfl_xor(tmx, m, 64));
    tmx = __builtin_amdgcn_readfirstlane(tmx);
    const int loopn = (tmx + 3) & ~3;

    unsigned uo = (unsigned)bidx * 64u + 4u * (unsigned)g;
#define LOADU(UB, OFF) do { \
        UB[0] = *(const f32x4*)(src + (OFF)); \
        UB[1] = *(const f32x4*)(src + (OFF) + 16); \
        UB[2] = *(const f32x4*)(src + (OFF) + 32); \
        UB[3] = *(const f32x4*)(src + (OFF) + 48); \
    } while (0)

    f32x4 U0[4], U1[4], U2[4], U3[4];
    LOADU(U0, uo);
    LOADU(U1, uo + 8192u);
    LOADU(U2, uo + 16384u);
    LOADU(U3, uo + 24576u);
    unsigned uo4 = uo + 32768u;
    int nt = 4;

    float C = 0.0f, snapC = 0.0f;
    unsigned snap0=0,snap1=0,snap2=0,snap3=0,snap4=0,snap5=0,snap6=0,snap7=0;

#define STEP(QQ, UB) do { \
        const int t_ = s + (QQ); \
        float w_[4][4]; \
        _Pragma("unroll") \
        for (int tt = 0; tt < 4; ++tt) { \
            _Pragma("unroll") \
            for (int r = 0; r < 4; ++r) \
                w_[tt][r] = D[tt][r] * (EUP ? UB[tt][r] : fexp2(UB[tt][r] * K)); \
        } \
        if (((t_) & 7) == 7) { \
            float m0 = fmaxf(fmaxf(w_[0][0], w_[0][1]), fmaxf(w_[0][2], w_[0][3])); \
            float m1 = fmaxf(fmaxf(w_[1][0], w_[1][1]), fmaxf(w_[1][2], w_[1][3])); \
            float m2 = fmaxf(fmaxf(w_[2][0], w_[2][1]), fmaxf(w_[2][2], w_[2][3])); \
            float m3 = fmaxf(fmaxf(w_[3][0], w_[3][1]), fmaxf(w_[3][2], w_[3][3])); \
            float mm = fmaxf(fmaxf(m0, m1), fmaxf(m2, m3)); \
            mm = fmaxf(mm, __shfl_xor(mm, 16, 64)); \
            mm = fmaxf(mm, __shfl_xor(mm, 32, 64)); \
            float inv_ = frcp(mm); \
            C += LN2 * flog2(mm); \
            _Pragma("unroll") \
            for (int tt = 0; tt < 4; ++tt) { \
                _Pragma("unroll") \
                for (int r = 0; r < 4; ++r) w_[tt][r] *= inv_; \
            } \
        } \
        unsigned p00 = cvtpk(w_[0][0], w_[0][1]), p01 = cvtpk(w_[0][2], w_[0][3]); \
        unsigned p10 = cvtpk(w_[1][0], w_[1][1]), p11 = cvtpk(w_[1][2], w_[1][3]); \
        unsigned p20 = cvtpk(w_[2][0], w_[2][1]), p21 = cvtpk(w_[2][2], w_[2][3]); \
        unsigned p30 = cvtpk(w_[3][0], w_[3][1]), p31 = cvtpk(w_[3][2], w_[3][3]); \
        swap32(p00, p10); swap32(p01, p11); swap32(p20, p30); swap32(p21, p31); \
        swap16(p00, p10); swap16(p01, p11); swap16(p20, p30); swap16(p21, p31); \
        if (__ballot(len == t_ + 1)) { \
            const bool cc = (len == t_ + 1); \
            snap0 = cc ? p00 : snap0; snap1 = cc ? p01 : snap1; \
            snap2 = cc ? p10 : snap2; snap3 = cc ? p11 : snap3; \
            snap4 = cc ? p20 : snap4; snap5 = cc ? p21 : snap5; \
            snap6 = cc ? p30 : snap6; snap7 = cc ? p31 : snap7; \
            snapC = cc ? C : snapC; \
        } \
        U8 b0_, b1_; \
        b0_.u[0] = p00; b0_.u[1] = p01; b0_.u[2] = p10; b0_.u[3] = p11; \
        b1_.u[0] = p20; b1_.u[1] = p21; b1_.u[2] = p30; b1_.u[3] = p31; \
        _Pragma("unroll") \
        for (int tt = 0; tt < 4; ++tt) { \
            f32x4 acc_ = __builtin_amdgcn_mfma_f32_16x16x32_bf16(EA[tt][0].v, b0_.v, zf, 0, 0, 0); \
            D[tt] = __builtin_amdgcn_mfma_f32_16x16x32_bf16(EA[tt][1].v, b1_.v, acc_, 0, 0, 0); \
        } \
        LOADU(UB, uo4); \
        uo4 += (nt < 255) ? 8192u : 0u; ++nt; \
    } while (0)

    for (int s = 0; s < loopn; s += 4) {
        STEP(0, U0);
        STEP(1, U1);
        STEP(2, U2);
        STEP(3, U3);
    }

    U8 w0_, w1_;
    w0_.u[0]=snap0; w0_.u[1]=snap1; w0_.u[2]=snap2; w0_.u[3]=snap3;
    w1_.u[0]=snap4; w1_.u[1]=snap5; w1_.u[2]=snap6; w1_.u[3]=snap7;
    f32x4 acc = __builtin_amdgcn_mfma_f32_16x16x32_bf16(AE[0].v, w0_.v, zf, 0, 0, 0);
    acc = __builtin_amdgcn_mfma_f32_16x16x32_bf16(AE[1].v, w1_.v, acc, 0, 0, 0);
    if (lane < 16) out[bidx] = snapC + LN2 * flog2(acc[0]);
}

extern "C" void kernel_launch(void* const* d_in, const int* in_sizes, int n_in,
                              void* d_out, int out_size, void* d_ws, size_t ws_size,
                              hipStream_t stream) {
    const float* unary   = (const float*)d_in[0];
    const float* trans   = (const float*)d_in[1];
    const int*   lengths = (const int*)d_in[2];
    float* out = (float*)d_out;

    const size_t need = (size_t)T_STEPS * B_SIZE * N_TAGS * sizeof(float);
    if (ws_size >= need) {
        float* eu = (float*)d_ws;
        // 2M elements, 1 float4 per thread: 2048 blocks x 256 threads.
        hipLaunchKernelGGL(expk_kernel, dim3(2048), dim3(256), 0, stream, unary, eu);
        hipLaunchKernelGGL(crf_mfma_kernel<true>, dim3(B_SIZE / 16), dim3(64), 0, stream,
                           eu, trans, lengths, out);
    } else {
        hipLaunchKernelGGL(crf_mfma_kernel<false>, dim3(B_SIZE / 16), dim3(64), 0, stream,
                           unary, trans, lengths, out);
    }
}

// Round 5
// 48.292 us; speedup vs baseline: 1.6879x; 1.4223x over previous
//
#include <hip/hip_runtime.h>

#define T_STEPS 256
#define B_SIZE  128
#define N_TAGS  64
#define BN_     8192      // B*N
#define START_IDX 1
#define END_IDX 2

typedef float  f32x4  __attribute__((ext_vector_type(4)));
typedef float  f32x2  __attribute__((ext_vector_type(2)));
typedef short  bf16x8 __attribute__((ext_vector_type(8)));

union U8 { unsigned u[4]; bf16x8 v; };
union F4 { f32x4 v; f32x2 h[2]; float f[4]; };

__device__ __forceinline__ float fexp2(float x){float r;asm("v_exp_f32 %0, %1":"=v"(r):"v"(x));return r;}
__device__ __forceinline__ float flog2(float x){float r;asm("v_log_f32 %0, %1":"=v"(r):"v"(x));return r;}
__device__ __forceinline__ float frcp(float x){float r;asm("v_rcp_f32 %0, %1":"=v"(r):"v"(x));return r;}
__device__ __forceinline__ unsigned cvtpk(float lo,float hi){unsigned r;asm("v_cvt_pk_bf16_f32 %0, %1, %2":"=v"(r):"v"(lo),"v"(hi));return r;}
__device__ __forceinline__ void swap32(unsigned &a, unsigned &b){asm("v_permlane32_swap_b32 %0, %1":"+v"(a),"+v"(b));}
__device__ __forceinline__ void swap16(unsigned &a, unsigned &b){asm("v_permlane16_swap_b32 %0, %1":"+v"(a),"+v"(b));}
__device__ __forceinline__ f32x2 pkmul(f32x2 a, f32x2 b){f32x2 r;asm("v_pk_mul_f32 %0, %1, %2":"=v"(r):"v"(a),"v"(b));return r;}

// Bulk: eu[i] = exp(unary[i]).  2M elems, 1 float4/thread.
__global__ void expk_kernel(const float* __restrict__ u, float* __restrict__ eu) {
    const float K = 1.4426950408889634f;
    size_t i = (size_t)blockIdx.x * blockDim.x + threadIdx.x;
    f32x4 v = *(const f32x4*)(u + 4 * i);
    f32x4 r;
    r[0] = fexp2(v[0] * K); r[1] = fexp2(v[1] * K);
    r[2] = fexp2(v[2] * K); r[3] = fexp2(v[3] * K);
    *(f32x4*)(eu + 4 * i) = r;
}

// One recurrence step: W = D ∘ U ; [rescale] ; [fwd snapshot] ; pack->swaps ; D = A·W.
template<bool EUP, bool RS, bool SNAPW>
__device__ __forceinline__ void stepfn(F4 (&D)[4], F4 (&UB)[4], const U8 (&A)[4][2],
                                       bool ccw, F4 (&wS)[4], float &snapC, float &C) {
    const float K = 1.4426950408889634f, LN2 = 0.6931471805599453f;
    const f32x4 zf = {0.f, 0.f, 0.f, 0.f};
    F4 W[4];
#pragma unroll
    for (int tt = 0; tt < 4; ++tt) {
        if (EUP) {
            W[tt].h[0] = pkmul(D[tt].h[0], UB[tt].h[0]);
            W[tt].h[1] = pkmul(D[tt].h[1], UB[tt].h[1]);
        } else {
#pragma unroll
            for (int r = 0; r < 4; ++r) W[tt].f[r] = D[tt].f[r] * fexp2(UB[tt].f[r] * K);
        }
    }
    if (RS) {
        float m0 = fmaxf(fmaxf(W[0].f[0], W[0].f[1]), fmaxf(W[0].f[2], W[0].f[3]));
        float m1 = fmaxf(fmaxf(W[1].f[0], W[1].f[1]), fmaxf(W[1].f[2], W[1].f[3]));
        float m2 = fmaxf(fmaxf(W[2].f[0], W[2].f[1]), fmaxf(W[2].f[2], W[2].f[3]));
        float m3 = fmaxf(fmaxf(W[3].f[0], W[3].f[1]), fmaxf(W[3].f[2], W[3].f[3]));
        float mm = fmaxf(fmaxf(m0, m1), fmaxf(m2, m3));
        mm = fmaxf(mm, __shfl_xor(mm, 16, 64));
        mm = fmaxf(mm, __shfl_xor(mm, 32, 64));
        float inv = frcp(mm);
        C += LN2 * flog2(mm);
        f32x2 iv; iv[0] = inv; iv[1] = inv;
#pragma unroll
        for (int tt = 0; tt < 4; ++tt) {
            W[tt].h[0] = pkmul(W[tt].h[0], iv);
            W[tt].h[1] = pkmul(W[tt].h[1], iv);
        }
    }
    if (SNAPW) {
        if (__ballot(ccw)) {
#pragma unroll
            for (int tt = 0; tt < 4; ++tt)
#pragma unroll
                for (int r = 0; r < 4; ++r)
                    wS[tt].f[r] = ccw ? W[tt].f[r] : wS[tt].f[r];
            snapC = ccw ? C : snapC;
        }
    }
    unsigned p00 = cvtpk(W[0].f[0], W[0].f[1]), p01 = cvtpk(W[0].f[2], W[0].f[3]);
    unsigned p10 = cvtpk(W[1].f[0], W[1].f[1]), p11 = cvtpk(W[1].f[2], W[1].f[3]);
    unsigned p20 = cvtpk(W[2].f[0], W[2].f[1]), p21 = cvtpk(W[2].f[2], W[2].f[3]);
    unsigned p30 = cvtpk(W[3].f[0], W[3].f[1]), p31 = cvtpk(W[3].f[2], W[3].f[3]);
    swap32(p00, p10); swap32(p01, p11); swap32(p20, p30); swap32(p21, p31);
    swap16(p00, p10); swap16(p01, p11); swap16(p20, p30); swap16(p21, p31);
    U8 b0, b1;
    b0.u[0] = p00; b0.u[1] = p01; b0.u[2] = p10; b0.u[3] = p11;
    b1.u[0] = p20; b1.u[1] = p21; b1.u[2] = p30; b1.u[3] = p31;
#pragma unroll
    for (int tt = 0; tt < 4; ++tt) {
        f32x4 acc = __builtin_amdgcn_mfma_f32_16x16x32_bf16(A[tt][0].v, b0.v, zf, 0, 0, 0);
        D[tt].v   = __builtin_amdgcn_mfma_f32_16x16x32_bf16(A[tt][1].v, b1.v, acc, 0, 0, 0);
    }
}

template<bool EUP>
__launch_bounds__(128, 1)
__global__ void crf_fb_kernel(const float* __restrict__ src,
                              const float* __restrict__ trans,
                              const int* __restrict__ lengths,
                              float* __restrict__ out) {
    const int tid  = threadIdx.x;
    const int wid  = tid >> 6;           // 0 = forward wave, 1 = backward wave
    const int lane = tid & 63;
    const int col  = lane & 15;          // batch within wave (MFMA col)
    const int g    = lane >> 4;
    const int bidx = blockIdx.x * 16 + col;

    __shared__ __align__(16) float sT[N_TAGS * N_TAGS];
    __shared__ __align__(16) float sW[N_TAGS * 16];
    __shared__ __align__(16) float sV[N_TAGS * 16];
    __shared__ float sCf[16], sCb[16];

    {
        const float4* t4 = (const float4*)trans;
        float4* s4 = (float4*)sT;
#pragma unroll
        for (int k2 = 0; k2 < 8; ++k2) s4[k2 * 128 + tid] = t4[k2 * 128 + tid];
    }
    __syncthreads();

    const float K   = 1.4426950408889634f;
    const float LN2 = 0.6931471805599453f;

    const int len = lengths[bidx];
    const int M   = (len - 1) >> 1;      // forward target step
    const int Kb  = (len - 1) - M;       // backward step count

    // Fragments: forward uses E = exp(trans) rows; backward uses E^T rows.
    U8 A[4][2];
    F4 D[4];
    if (wid == 0) {
#pragma unroll
        for (int tt = 0; tt < 4; ++tt)
#pragma unroll
            for (int c = 0; c < 2; ++c) {
                const float* p = &sT[(16*tt + col)*64 + 32*c + 8*g];
#pragma unroll
                for (int j2 = 0; j2 < 4; ++j2)
                    A[tt][c].u[j2] = cvtpk(fexp2(p[2*j2]*K), fexp2(p[2*j2+1]*K));
            }
#pragma unroll
        for (int tt = 0; tt < 4; ++tt)
#pragma unroll
            for (int r = 0; r < 4; ++r)
                D[tt].f[r] = fexp2(sT[(16*tt + 4*g + r)*64 + START_IDX] * K);
    } else {
#pragma unroll
        for (int tt = 0; tt < 4; ++tt)
#pragma unroll
            for (int c = 0; c < 2; ++c) {
#pragma unroll
                for (int j2 = 0; j2 < 4; ++j2) {
                    const int a0 = 32*c + 8*g + 2*j2;
                    A[tt][c].u[j2] = cvtpk(fexp2(sT[a0*64 + 16*tt + col] * K),
                                           fexp2(sT[(a0+1)*64 + 16*tt + col] * K));
                }
            }
#pragma unroll
        for (int tt = 0; tt < 4; ++tt)
#pragma unroll
            for (int r = 0; r < 4; ++r)
                D[tt].f[r] = fexp2(sT[END_IDX*64 + 16*tt + 4*g + r] * K);
    }

    // Wave-max iteration count.
    int need = (wid == 0) ? (M + 1) : Kb;
    int mx = need;
#pragma unroll
    for (int m = 1; m < 64; m <<= 1) mx = max(mx, __shfl_xor(mx, m, 64));
    mx = __builtin_amdgcn_readfirstlane(mx);

    const int base = bidx * 64 + 4 * g;   // per-lane elem offset (n-offset 16*tt via imm)

#define LOAD4(RB, OFF) do { \
        RB[0].v = *(const f32x4*)(src + (OFF)); \
        RB[1].v = *(const f32x4*)(src + (OFF) + 16); \
        RB[2].v = *(const f32x4*)(src + (OFF) + 32); \
        RB[3].v = *(const f32x4*)(src + (OFF) + 48); \
    } while (0)

    float C = 0.0f, snapC = 0.0f;
    F4 wS[4];
#pragma unroll
    for (int tt = 0; tt < 4; ++tt) wS[tt] = D[tt];   // covers bwd Kb==0 (len==1)

    F4 R0[4], R1[4], R2[4], R3[4], R4_[4], R5[4], R6[4], R7[4];

    if (wid == 0) {
        // ---------------- forward: t_ = 0 .. Nf-1 (consumes eu_t) ----------------
        LOAD4(R0, base);            LOAD4(R1, base + BN_);
        LOAD4(R2, base + 2*BN_);    LOAD4(R3, base + 3*BN_);
        LOAD4(R4_, base + 4*BN_);   LOAD4(R5, base + 5*BN_);
        LOAD4(R6, base + 6*BN_);    LOAD4(R7, base + 7*BN_);
        int offF = base + 8 * BN_;
        const int Nf = ((mx) + 7) & ~7;          // mx = Mmax+1 >= 1
        for (int s = 0; s < Nf; s += 8) {
#define FSTEP(QQ, RB, RSF) do { \
            const int t_ = s + (QQ); \
            stepfn<EUP, RSF, true>(D, RB, A, (t_ == M), wS, snapC, C); \
            LOAD4(RB, offF); offF += BN_; \
        } while (0)
            FSTEP(0, R0, false); FSTEP(1, R1, false); FSTEP(2, R2, false);
            FSTEP(3, R3, false); FSTEP(4, R4_, false); FSTEP(5, R5, false);
            FSTEP(6, R6, false); FSTEP(7, R7, true);
#undef FSTEP
        }
    } else {
        // -------- backward: iter k = 1..Nb consumes eu_{len-k} (per-lane t) --------
        {
#define PRIME(RB, q) do { int tq = max(len - 1 - (q), 0); LOAD4(RB, base + tq * BN_); } while (0)
            PRIME(R0, 0); PRIME(R1, 1); PRIME(R2, 2); PRIME(R3, 3);
            PRIME(R4_, 4); PRIME(R5, 5); PRIME(R6, 6); PRIME(R7, 7);
#undef PRIME
        }
        int tP = len - 9;
        const int Nb = ((mx) + 7) & ~7;          // mx = Kmax, may be 0
        for (int s = 0; s < Nb; s += 8) {
#define BSTEP(QQ, RB, RSF) do { \
            const int k_ = s + (QQ) + 1; \
            stepfn<EUP, RSF, false>(D, RB, A, false, wS, snapC, C); \
            if (__ballot(k_ == Kb)) { \
                const bool cc = (k_ == Kb); \
                _Pragma("unroll") \
                for (int tt = 0; tt < 4; ++tt) { \
                    _Pragma("unroll") \
                    for (int r = 0; r < 4; ++r) \
                        wS[tt].f[r] = cc ? D[tt].f[r] : wS[tt].f[r]; \
                } \
                snapC = cc ? C : snapC; \
            } \
            int tc = max(tP, 0); LOAD4(RB, base + tc * BN_); tP -= 1; \
        } while (0)
            BSTEP(0, R0, false); BSTEP(1, R1, false); BSTEP(2, R2, false);
            BSTEP(3, R3, false); BSTEP(4, R4_, false); BSTEP(5, R5, false);
            BSTEP(6, R6, false); BSTEP(7, R7, true);
#undef BSTEP
        }
    }

    // ---------------- combine: Z[b] = exp(Cf+Cb) * sum_n w_M[n] * v_M[n] ----------------
    {
        float* dst = (wid == 0) ? sW : sV;
#pragma unroll
        for (int tt = 0; tt < 4; ++tt)
#pragma unroll
            for (int r = 0; r < 4; ++r)
                dst[(16*tt + 4*g + r) * 16 + col] = wS[tt].f[r];
        if (g == 0) { if (wid == 0) sCf[col] = snapC; else sCb[col] = snapC; }
    }
    __syncthreads();
    if (wid == 0) {
        float part = 0.0f;
#pragma unroll
        for (int j = 0; j < 16; ++j) {
            const int n = g * 16 + j;
            part = fmaf(sW[n * 16 + col], sV[n * 16 + col], part);
        }
        part += __shfl_xor(part, 16, 64);
        part += __shfl_xor(part, 32, 64);
        if (g == 0) out[bidx] = sCf[col] + sCb[col] + LN2 * flog2(part);
    }
#undef LOAD4
}

extern "C" void kernel_launch(void* const* d_in, const int* in_sizes, int n_in,
                              void* d_out, int out_size, void* d_ws, size_t ws_size,
                              hipStream_t stream) {
    const float* unary   = (const float*)d_in[0];
    const float* trans   = (const float*)d_in[1];
    const int*   lengths = (const int*)d_in[2];
    float* out = (float*)d_out;

    const size_t need = (size_t)T_STEPS * B_SIZE * N_TAGS * sizeof(float);
    if (ws_size >= need) {
        float* eu = (float*)d_ws;
        hipLaunchKernelGGL(expk_kernel, dim3(2048), dim3(256), 0, stream, unary, eu);
        hipLaunchKernelGGL(crf_fb_kernel<true>, dim3(B_SIZE / 16), dim3(128), 0, stream,
                           eu, trans, lengths, out);
    } else {
        hipLaunchKernelGGL(crf_fb_kernel<false>, dim3(B_SIZE / 16), dim3(128), 0, stream,
                           unary, trans, lengths, out);
    }
}

// Round 6
// 45.388 us; speedup vs baseline: 1.7959x; 1.0640x over previous
//
#include <hip/hip_runtime.h>

#define T_STEPS 256
#define B_SIZE  128
#define N_TAGS  64
#define BN_     8192      // B*N
#define START_IDX 1
#define END_IDX 2

typedef float  f32x4  __attribute__((ext_vector_type(4)));
typedef float  f32x2  __attribute__((ext_vector_type(2)));
typedef short  bf16x8 __attribute__((ext_vector_type(8)));

union U8 { unsigned u[4]; bf16x8 v; };
union F4 { f32x4 v; f32x2 h[2]; float f[4]; };

__device__ __forceinline__ float fexp2(float x){float r;asm("v_exp_f32 %0, %1":"=v"(r):"v"(x));return r;}
__device__ __forceinline__ float flog2(float x){float r;asm("v_log_f32 %0, %1":"=v"(r):"v"(x));return r;}
__device__ __forceinline__ float frcp(float x){float r;asm("v_rcp_f32 %0, %1":"=v"(r):"v"(x));return r;}
__device__ __forceinline__ unsigned cvtpk(float lo,float hi){unsigned r;asm("v_cvt_pk_bf16_f32 %0, %1, %2":"=v"(r):"v"(lo),"v"(hi));return r;}
__device__ __forceinline__ void swap32(unsigned &a, unsigned &b){asm("v_permlane32_swap_b32 %0, %1":"+v"(a),"+v"(b));}
__device__ __forceinline__ void swap16(unsigned &a, unsigned &b){asm("v_permlane16_swap_b32 %0, %1":"+v"(a),"+v"(b));}
__device__ __forceinline__ f32x2 pkmul(f32x2 a, f32x2 b){f32x2 r;asm("v_pk_mul_f32 %0, %1, %2":"=v"(r):"v"(a),"v"(b));return r;}

// Pinned async loads: volatile asm keeps issue position + keeps ring registers live.
#define LOAD4A(RB, PTR) do { const float* _p = (PTR); \
    asm volatile("global_load_dwordx4 %0, %1, off"            : "=v"(RB[0].v) : "v"(_p)); \
    asm volatile("global_load_dwordx4 %0, %1, off offset:64"  : "=v"(RB[1].v) : "v"(_p)); \
    asm volatile("global_load_dwordx4 %0, %1, off offset:128" : "=v"(RB[2].v) : "v"(_p)); \
    asm volatile("global_load_dwordx4 %0, %1, off offset:192" : "=v"(RB[3].v) : "v"(_p)); \
} while (0)

__device__ __forceinline__ void wait28() {
    asm volatile("s_waitcnt vmcnt(28)" ::: "memory");
    __builtin_amdgcn_sched_barrier(0);
}
__device__ __forceinline__ void wait0() {
    asm volatile("s_waitcnt vmcnt(0)" ::: "memory");
    __builtin_amdgcn_sched_barrier(0);
}

// Bulk: eu[i] = exp(unary[i]).  2M elems, 1 float4/thread.
__global__ void expk_kernel(const float* __restrict__ u, float* __restrict__ eu) {
    const float K = 1.4426950408889634f;
    size_t i = (size_t)blockIdx.x * blockDim.x + threadIdx.x;
    f32x4 v = *(const f32x4*)(u + 4 * i);
    f32x4 r;
    r[0] = fexp2(v[0] * K); r[1] = fexp2(v[1] * K);
    r[2] = fexp2(v[2] * K); r[3] = fexp2(v[3] * K);
    *(f32x4*)(eu + 4 * i) = r;
}

// One recurrence step: W = D ∘ U ; [rescale] ; [fwd snapshot] ; pack->swaps ; D = A·W.
template<bool EUP, bool RS, bool SNAPW>
__device__ __forceinline__ void stepfn(F4 (&D)[4], F4 (&UB)[4], const U8 (&A)[4][2],
                                       bool ccw, F4 (&wS)[4], float &snapC, float &C) {
    const float K = 1.4426950408889634f, LN2 = 0.6931471805599453f;
    const f32x4 zf = {0.f, 0.f, 0.f, 0.f};
    F4 W[4];
#pragma unroll
    for (int tt = 0; tt < 4; ++tt) {
        if (EUP) {
            W[tt].h[0] = pkmul(D[tt].h[0], UB[tt].h[0]);
            W[tt].h[1] = pkmul(D[tt].h[1], UB[tt].h[1]);
        } else {
#pragma unroll
            for (int r = 0; r < 4; ++r) W[tt].f[r] = D[tt].f[r] * fexp2(UB[tt].f[r] * K);
        }
    }
    if (RS) {
        float m0 = fmaxf(fmaxf(W[0].f[0], W[0].f[1]), fmaxf(W[0].f[2], W[0].f[3]));
        float m1 = fmaxf(fmaxf(W[1].f[0], W[1].f[1]), fmaxf(W[1].f[2], W[1].f[3]));
        float m2 = fmaxf(fmaxf(W[2].f[0], W[2].f[1]), fmaxf(W[2].f[2], W[2].f[3]));
        float m3 = fmaxf(fmaxf(W[3].f[0], W[3].f[1]), fmaxf(W[3].f[2], W[3].f[3]));
        float mm = fmaxf(fmaxf(m0, m1), fmaxf(m2, m3));
        mm = fmaxf(mm, __shfl_xor(mm, 16, 64));
        mm = fmaxf(mm, __shfl_xor(mm, 32, 64));
        float inv = frcp(mm);
        C += LN2 * flog2(mm);
        f32x2 iv; iv[0] = inv; iv[1] = inv;
#pragma unroll
        for (int tt = 0; tt < 4; ++tt) {
            W[tt].h[0] = pkmul(W[tt].h[0], iv);
            W[tt].h[1] = pkmul(W[tt].h[1], iv);
        }
    }
    if (SNAPW) {
        if (__ballot(ccw)) {
#pragma unroll
            for (int tt = 0; tt < 4; ++tt)
#pragma unroll
                for (int r = 0; r < 4; ++r)
                    wS[tt].f[r] = ccw ? W[tt].f[r] : wS[tt].f[r];
            snapC = ccw ? C : snapC;
        }
    }
    unsigned p00 = cvtpk(W[0].f[0], W[0].f[1]), p01 = cvtpk(W[0].f[2], W[0].f[3]);
    unsigned p10 = cvtpk(W[1].f[0], W[1].f[1]), p11 = cvtpk(W[1].f[2], W[1].f[3]);
    unsigned p20 = cvtpk(W[2].f[0], W[2].f[1]), p21 = cvtpk(W[2].f[2], W[2].f[3]);
    unsigned p30 = cvtpk(W[3].f[0], W[3].f[1]), p31 = cvtpk(W[3].f[2], W[3].f[3]);
    swap32(p00, p10); swap32(p01, p11); swap32(p20, p30); swap32(p21, p31);
    swap16(p00, p10); swap16(p01, p11); swap16(p20, p30); swap16(p21, p31);
    U8 b0, b1;
    b0.u[0] = p00; b0.u[1] = p01; b0.u[2] = p10; b0.u[3] = p11;
    b1.u[0] = p20; b1.u[1] = p21; b1.u[2] = p30; b1.u[3] = p31;
#pragma unroll
    for (int tt = 0; tt < 4; ++tt) {
        f32x4 acc = __builtin_amdgcn_mfma_f32_16x16x32_bf16(A[tt][0].v, b0.v, zf, 0, 0, 0);
        D[tt].v   = __builtin_amdgcn_mfma_f32_16x16x32_bf16(A[tt][1].v, b1.v, acc, 0, 0, 0);
    }
}

template<bool EUP>
__launch_bounds__(128, 1)
__global__ void crf_fb_kernel(const float* __restrict__ src,
                              const float* __restrict__ trans,
                              const int* __restrict__ lengths,
                              float* __restrict__ out) {
    const int tid  = threadIdx.x;
    const int wid  = tid >> 6;           // 0 = forward wave, 1 = backward wave
    const int lane = tid & 63;
    const int col  = lane & 15;          // batch within wave (MFMA col)
    const int g    = lane >> 4;
    const int bidx = blockIdx.x * 16 + col;

    __shared__ __align__(16) float sT[N_TAGS * N_TAGS];
    __shared__ __align__(16) float sW[N_TAGS * 16];
    __shared__ __align__(16) float sV[N_TAGS * 16];
    __shared__ float sCf[16], sCb[16];

    {
        const float4* t4 = (const float4*)trans;
        float4* s4 = (float4*)sT;
#pragma unroll
        for (int k2 = 0; k2 < 8; ++k2) s4[k2 * 128 + tid] = t4[k2 * 128 + tid];
    }
    __syncthreads();

    const float K   = 1.4426950408889634f;
    const float LN2 = 0.6931471805599453f;

    const int len = lengths[bidx];
    const int M   = (len - 1) >> 1;      // forward target step
    const int Kb  = (len - 1) - M;       // backward step count

    // Fragments: forward uses E = exp(trans) rows; backward uses E^T rows.
    U8 A[4][2];
    F4 D[4];
    if (wid == 0) {
#pragma unroll
        for (int tt = 0; tt < 4; ++tt)
#pragma unroll
            for (int c = 0; c < 2; ++c) {
                const float* p = &sT[(16*tt + col)*64 + 32*c + 8*g];
#pragma unroll
                for (int j2 = 0; j2 < 4; ++j2)
                    A[tt][c].u[j2] = cvtpk(fexp2(p[2*j2]*K), fexp2(p[2*j2+1]*K));
            }
#pragma unroll
        for (int tt = 0; tt < 4; ++tt)
#pragma unroll
            for (int r = 0; r < 4; ++r)
                D[tt].f[r] = fexp2(sT[(16*tt + 4*g + r)*64 + START_IDX] * K);
    } else {
#pragma unroll
        for (int tt = 0; tt < 4; ++tt)
#pragma unroll
            for (int c = 0; c < 2; ++c) {
#pragma unroll
                for (int j2 = 0; j2 < 4; ++j2) {
                    const int a0 = 32*c + 8*g + 2*j2;
                    A[tt][c].u[j2] = cvtpk(fexp2(sT[a0*64 + 16*tt + col] * K),
                                           fexp2(sT[(a0+1)*64 + 16*tt + col] * K));
                }
            }
#pragma unroll
        for (int tt = 0; tt < 4; ++tt)
#pragma unroll
            for (int r = 0; r < 4; ++r)
                D[tt].f[r] = fexp2(sT[END_IDX*64 + 16*tt + 4*g + r] * K);
    }

    // Wave-max iteration count.
    int need = (wid == 0) ? (M + 1) : Kb;
    int mx = need;
#pragma unroll
    for (int m = 1; m < 64; m <<= 1) mx = max(mx, __shfl_xor(mx, m, 64));
    mx = __builtin_amdgcn_readfirstlane(mx);

    const int base = bidx * 64 + 4 * g;

    float C = 0.0f, snapC = 0.0f;
    F4 wS[4];
#pragma unroll
    for (int tt = 0; tt < 4; ++tt) wS[tt] = D[tt];   // covers bwd Kb==0 (len==1)

    F4 R0[4], R1[4], R2[4], R3[4], R4_[4], R5[4], R6[4], R7[4];

    if (wid == 0) {
        // ---------------- forward: t_ = 0 .. Nf-1 (consumes eu_t) ----------------
        const float* pf = src + base;
        LOAD4A(R0, pf);            LOAD4A(R1, pf + BN_);
        LOAD4A(R2, pf + 2*BN_);    LOAD4A(R3, pf + 3*BN_);
        LOAD4A(R4_, pf + 4*BN_);   LOAD4A(R5, pf + 5*BN_);
        LOAD4A(R6, pf + 6*BN_);    LOAD4A(R7, pf + 7*BN_);
        const float* pn = pf + 8 * BN_;
        const int Nf = (mx + 7) & ~7;            // mx = Mmax+1 >= 1; Nf+8 <= 256
        for (int s = 0; s < Nf; s += 8) {
#define FSTEP(QQ, RB, RSF) do { \
            const int t_ = s + (QQ); \
            wait28(); \
            stepfn<EUP, RSF, true>(D, RB, A, (t_ == M), wS, snapC, C); \
            LOAD4A(RB, pn); pn += BN_; \
        } while (0)
            FSTEP(0, R0, false); FSTEP(1, R1, false); FSTEP(2, R2, false);
            FSTEP(3, R3, false); FSTEP(4, R4_, false); FSTEP(5, R5, false);
            FSTEP(6, R6, false); FSTEP(7, R7, true);
#undef FSTEP
        }
        wait0();
    } else {
        // -------- backward: iter k = 1..Nb consumes eu_{len-k} (per-lane t) --------
        const float* pb = src + base;
        {
#define PRIME(RB, q) do { int tq = max(len - 1 - (q), 0); LOAD4A(RB, pb + tq * BN_); } while (0)
            PRIME(R0, 0); PRIME(R1, 1); PRIME(R2, 2); PRIME(R3, 3);
            PRIME(R4_, 4); PRIME(R5, 5); PRIME(R6, 6); PRIME(R7, 7);
#undef PRIME
        }
        int tP = len - 9;
        const int Nb = (mx + 7) & ~7;            // mx = Kmax, may be 0
        for (int s = 0; s < Nb; s += 8) {
#define BSTEP(QQ, RB, RSF) do { \
            const int k_ = s + (QQ) + 1; \
            wait28(); \
            stepfn<EUP, RSF, false>(D, RB, A, false, wS, snapC, C); \
            if (__ballot(k_ == Kb)) { \
                const bool cc = (k_ == Kb); \
                _Pragma("unroll") \
                for (int tt = 0; tt < 4; ++tt) { \
                    _Pragma("unroll") \
                    for (int r = 0; r < 4; ++r) \
                        wS[tt].f[r] = cc ? D[tt].f[r] : wS[tt].f[r]; \
                } \
                snapC = cc ? C : snapC; \
            } \
            int tc = max(tP, 0); LOAD4A(RB, pb + tc * BN_); tP -= 1; \
        } while (0)
            BSTEP(0, R0, false); BSTEP(1, R1, false); BSTEP(2, R2, false);
            BSTEP(3, R3, false); BSTEP(4, R4_, false); BSTEP(5, R5, false);
            BSTEP(6, R6, false); BSTEP(7, R7, true);
#undef BSTEP
        }
        wait0();
    }

    // ---------------- combine: Z[b] = exp(Cf+Cb) * sum_n w_M[n] * v_M[n] ----------------
    {
        float* dst = (wid == 0) ? sW : sV;
#pragma unroll
        for (int tt = 0; tt < 4; ++tt)
#pragma unroll
            for (int r = 0; r < 4; ++r)
                dst[(16*tt + 4*g + r) * 16 + col] = wS[tt].f[r];
        if (g == 0) { if (wid == 0) sCf[col] = snapC; else sCb[col] = snapC; }
    }
    __syncthreads();
    if (wid == 0) {
        float part = 0.0f;
#pragma unroll
        for (int j = 0; j < 16; ++j) {
            const int n = g * 16 + j;
            part = fmaf(sW[n * 16 + col], sV[n * 16 + col], part);
        }
        part += __shfl_xor(part, 16, 64);
        part += __shfl_xor(part, 32, 64);
        if (g == 0) out[bidx] = sCf[col] + sCb[col] + LN2 * flog2(part);
    }
}

extern "C" void kernel_launch(void* const* d_in, const int* in_sizes, int n_in,
                              void* d_out, int out_size, void* d_ws, size_t ws_size,
                              hipStream_t stream) {
    const float* unary   = (const float*)d_in[0];
    const float* trans   = (const float*)d_in[1];
    const int*   lengths = (const int*)d_in[2];
    float* out = (float*)d_out;

    const size_t need = (size_t)T_STEPS * B_SIZE * N_TAGS * sizeof(float);
    if (ws_size >= need) {
        float* eu = (float*)d_ws;
        hipLaunchKernelGGL(expk_kernel, dim3(2048), dim3(256), 0, stream, unary, eu);
        hipLaunchKernelGGL(crf_fb_kernel<true>, dim3(B_SIZE / 16), dim3(128), 0, stream,
                           eu, trans, lengths, out);
    } else {
        hipLaunchKernelGGL(crf_fb_kernel<false>, dim3(B_SIZE / 16), dim3(128), 0, stream,
                           unary, trans, lengths, out);
    }
}

// Round 7
// 45.238 us; speedup vs baseline: 1.8018x; 1.0033x over previous
//
#include <hip/hip_runtime.h>

#define T_STEPS 256
#define B_SIZE  128
#define N_TAGS  64
#define BN_     8192      // B*N
#define KSLOTS  272       // time slots per direction in staged buffer
#define START_IDX 1
#define END_IDX 2

typedef float  f32x4  __attribute__((ext_vector_type(4)));
typedef float  f32x2  __attribute__((ext_vector_type(2)));
typedef short  bf16x8 __attribute__((ext_vector_type(8)));

union U8 { unsigned u[4]; bf16x8 v; };
union F4 { f32x4 v; f32x2 h[2]; float f[4]; };

__device__ __forceinline__ float fexp2(float x){float r;asm("v_exp_f32 %0, %1":"=v"(r):"v"(x));return r;}
__device__ __forceinline__ float flog2(float x){float r;asm("v_log_f32 %0, %1":"=v"(r):"v"(x));return r;}
__device__ __forceinline__ float frcp(float x){float r;asm("v_rcp_f32 %0, %1":"=v"(r):"v"(x));return r;}
__device__ __forceinline__ unsigned cvtpk(float lo,float hi){unsigned r;asm("v_cvt_pk_bf16_f32 %0, %1, %2":"=v"(r):"v"(lo),"v"(hi));return r;}
__device__ __forceinline__ void swap32(unsigned &a, unsigned &b){asm("v_permlane32_swap_b32 %0, %1":"+v"(a),"+v"(b));}
__device__ __forceinline__ void swap16(unsigned &a, unsigned &b){asm("v_permlane16_swap_b32 %0, %1":"+v"(a),"+v"(b));}
__device__ __forceinline__ f32x2 pkmul(f32x2 a, f32x2 b){f32x2 r;asm("v_pk_mul_f32 %0, %1, %2":"=v"(r):"v"(a),"v"(b));return r;}

// Staged-layout loads: lane reads 16B at tile + lane*16, tt-subtiles 1KB apart. Coalesced.
#define LOAD4N(RB, PTR) do { const float* _p = (PTR); \
    asm volatile("global_load_dwordx4 %0, %1, off"             : "=v"(RB[0].v) : "v"(_p)); \
    asm volatile("global_load_dwordx4 %0, %1, off offset:1024" : "=v"(RB[1].v) : "v"(_p)); \
    asm volatile("global_load_dwordx4 %0, %1, off offset:2048" : "=v"(RB[2].v) : "v"(_p)); \
    asm volatile("global_load_dwordx4 %0, %1, off offset:3072" : "=v"(RB[3].v) : "v"(_p)); \
} while (0)
// Old direct layout (fallback path only).
#define LOAD4O(RB, PTR) do { const float* _p = (PTR); \
    asm volatile("global_load_dwordx4 %0, %1, off"            : "=v"(RB[0].v) : "v"(_p)); \
    asm volatile("global_load_dwordx4 %0, %1, off offset:64"  : "=v"(RB[1].v) : "v"(_p)); \
    asm volatile("global_load_dwordx4 %0, %1, off offset:128" : "=v"(RB[2].v) : "v"(_p)); \
    asm volatile("global_load_dwordx4 %0, %1, off offset:192" : "=v"(RB[3].v) : "v"(_p)); \
} while (0)

__device__ __forceinline__ void wait28() {
    asm volatile("s_waitcnt vmcnt(28)" ::: "memory");
    __builtin_amdgcn_sched_barrier(0);
}
__device__ __forceinline__ void wait0() {
    asm volatile("s_waitcnt vmcnt(0)" ::: "memory");
    __builtin_amdgcn_sched_barrier(0);
}

// ---------------- prep: eu staged in per-lane fragment layout ----------------
// tile id = (dir*KSLOTS + k)*8 + blk ; tile holds 4 tt-subtiles of 64 lanes x 16B.
// dir 0: t = min(k, T-1).  dir 1: t = max(len_b - k, 0)  (per-batch shift).
__global__ void prep_kernel(const float* __restrict__ u,
                            const int* __restrict__ lengths,
                            float* __restrict__ dst) {
    const float K = 1.4426950408889634f;
    const int id   = blockIdx.x;
    const int blk  = id & 7;
    const int rem  = id >> 3;                 // dir*KSLOTS + k
    const int dir  = rem / KSLOTS;
    const int k    = rem - dir * KSLOTS;
    const int lane = threadIdx.x;
    const int col  = lane & 15;
    const int g    = lane >> 4;
    const int b    = blk * 16 + col;

    int t;
    if (dir == 0) t = min(k, T_STEPS - 1);
    else          t = max(lengths[b] - k, 0);

    const float* src = u + ((size_t)t * B_SIZE + b) * N_TAGS + 4 * g;
    float* d = dst + (size_t)id * 1024 + lane * 4;
#pragma unroll
    for (int tt = 0; tt < 4; ++tt) {
        f32x4 v = *(const f32x4*)(src + 16 * tt);
        f32x4 r;
        r[0] = fexp2(v[0] * K); r[1] = fexp2(v[1] * K);
        r[2] = fexp2(v[2] * K); r[3] = fexp2(v[3] * K);
        *(f32x4*)(d + tt * 256) = r;
    }
}

// Bulk exp only (fallback path).
__global__ void expk_kernel(const float* __restrict__ u, float* __restrict__ eu) {
    const float K = 1.4426950408889634f;
    size_t i = (size_t)blockIdx.x * blockDim.x + threadIdx.x;
    f32x4 v = *(const f32x4*)(u + 4 * i);
    f32x4 r;
    r[0] = fexp2(v[0] * K); r[1] = fexp2(v[1] * K);
    r[2] = fexp2(v[2] * K); r[3] = fexp2(v[3] * K);
    *(f32x4*)(eu + 4 * i) = r;
}

// One recurrence step: W = D ∘ U ; [rescale] ; [fwd snapshot] ; pack->swaps ; D = A·W.
template<bool EUP, bool RS, bool SNAPW>
__device__ __forceinline__ void stepfn(F4 (&D)[4], F4 (&UB)[4], const U8 (&A)[4][2],
                                       bool ccw, F4 (&wS)[4], float &snapC, float &C) {
    const float K = 1.4426950408889634f, LN2 = 0.6931471805599453f;
    const f32x4 zf = {0.f, 0.f, 0.f, 0.f};
    F4 W[4];
#pragma unroll
    for (int tt = 0; tt < 4; ++tt) {
        if (EUP) {
            W[tt].h[0] = pkmul(D[tt].h[0], UB[tt].h[0]);
            W[tt].h[1] = pkmul(D[tt].h[1], UB[tt].h[1]);
        } else {
#pragma unroll
            for (int r = 0; r < 4; ++r) W[tt].f[r] = D[tt].f[r] * fexp2(UB[tt].f[r] * K);
        }
    }
    if (RS) {
        float m0 = fmaxf(fmaxf(W[0].f[0], W[0].f[1]), fmaxf(W[0].f[2], W[0].f[3]));
        float m1 = fmaxf(fmaxf(W[1].f[0], W[1].f[1]), fmaxf(W[1].f[2], W[1].f[3]));
        float m2 = fmaxf(fmaxf(W[2].f[0], W[2].f[1]), fmaxf(W[2].f[2], W[2].f[3]));
        float m3 = fmaxf(fmaxf(W[3].f[0], W[3].f[1]), fmaxf(W[3].f[2], W[3].f[3]));
        float mm = fmaxf(fmaxf(m0, m1), fmaxf(m2, m3));
        mm = fmaxf(mm, __shfl_xor(mm, 16, 64));
        mm = fmaxf(mm, __shfl_xor(mm, 32, 64));
        float inv = frcp(mm);
        C += LN2 * flog2(mm);
        f32x2 iv; iv[0] = inv; iv[1] = inv;
#pragma unroll
        for (int tt = 0; tt < 4; ++tt) {
            W[tt].h[0] = pkmul(W[tt].h[0], iv);
            W[tt].h[1] = pkmul(W[tt].h[1], iv);
        }
    }
    if (SNAPW) {
        if (__ballot(ccw)) {
#pragma unroll
            for (int tt = 0; tt < 4; ++tt)
#pragma unroll
                for (int r = 0; r < 4; ++r)
                    wS[tt].f[r] = ccw ? W[tt].f[r] : wS[tt].f[r];
            snapC = ccw ? C : snapC;
        }
    }
    unsigned p00 = cvtpk(W[0].f[0], W[0].f[1]), p01 = cvtpk(W[0].f[2], W[0].f[3]);
    unsigned p10 = cvtpk(W[1].f[0], W[1].f[1]), p11 = cvtpk(W[1].f[2], W[1].f[3]);
    unsigned p20 = cvtpk(W[2].f[0], W[2].f[1]), p21 = cvtpk(W[2].f[2], W[2].f[3]);
    unsigned p30 = cvtpk(W[3].f[0], W[3].f[1]), p31 = cvtpk(W[3].f[2], W[3].f[3]);
    swap32(p00, p10); swap32(p01, p11); swap32(p20, p30); swap32(p21, p31);
    swap16(p00, p10); swap16(p01, p11); swap16(p20, p30); swap16(p21, p31);
    U8 b0, b1;
    b0.u[0] = p00; b0.u[1] = p01; b0.u[2] = p10; b0.u[3] = p11;
    b1.u[0] = p20; b1.u[1] = p21; b1.u[2] = p30; b1.u[3] = p31;
#pragma unroll
    for (int tt = 0; tt < 4; ++tt) {
        f32x4 acc = __builtin_amdgcn_mfma_f32_16x16x32_bf16(A[tt][0].v, b0.v, zf, 0, 0, 0);
        D[tt].v   = __builtin_amdgcn_mfma_f32_16x16x32_bf16(A[tt][1].v, b1.v, acc, 0, 0, 0);
    }
}

// Shared setup: fragments, seed, per-wave max count.  (same math as R6)
__device__ __forceinline__ void make_frags(const float* sT, int wid, int col, int g,
                                           U8 (&A)[4][2], F4 (&D)[4]) {
    const float K = 1.4426950408889634f;
    if (wid == 0) {
#pragma unroll
        for (int tt = 0; tt < 4; ++tt)
#pragma unroll
            for (int c = 0; c < 2; ++c) {
                const float* p = &sT[(16*tt + col)*64 + 32*c + 8*g];
#pragma unroll
                for (int j2 = 0; j2 < 4; ++j2)
                    A[tt][c].u[j2] = cvtpk(fexp2(p[2*j2]*K), fexp2(p[2*j2+1]*K));
            }
#pragma unroll
        for (int tt = 0; tt < 4; ++tt)
#pragma unroll
            for (int r = 0; r < 4; ++r)
                D[tt].f[r] = fexp2(sT[(16*tt + 4*g + r)*64 + START_IDX] * K);
    } else {
#pragma unroll
        for (int tt = 0; tt < 4; ++tt)
#pragma unroll
            for (int c = 0; c < 2; ++c) {
#pragma unroll
                for (int j2 = 0; j2 < 4; ++j2) {
                    const int a0 = 32*c + 8*g + 2*j2;
                    A[tt][c].u[j2] = cvtpk(fexp2(sT[a0*64 + 16*tt + col] * K),
                                           fexp2(sT[(a0+1)*64 + 16*tt + col] * K));
                }
            }
#pragma unroll
        for (int tt = 0; tt < 4; ++tt)
#pragma unroll
            for (int r = 0; r < 4; ++r)
                D[tt].f[r] = fexp2(sT[END_IDX*64 + 16*tt + 4*g + r] * K);
    }
}

// ---------------- serial kernel, staged layout (coalesced loads, uniform k) ----------------
__launch_bounds__(128, 1)
__global__ void crf_fb_kernel(const float* __restrict__ stg,
                              const float* __restrict__ trans,
                              const int* __restrict__ lengths,
                              float* __restrict__ out) {
    const int tid  = threadIdx.x;
    const int wid  = tid >> 6;
    const int lane = tid & 63;
    const int col  = lane & 15;
    const int g    = lane >> 4;
    const int blk  = blockIdx.x;
    const int bidx = blk * 16 + col;

    __shared__ __align__(16) float sT[N_TAGS * N_TAGS];
    __shared__ __align__(16) float sW[N_TAGS * 16];
    __shared__ __align__(16) float sV[N_TAGS * 16];
    __shared__ float sCf[16], sCb[16];

    {
        const float4* t4 = (const float4*)trans;
        float4* s4 = (float4*)sT;
#pragma unroll
        for (int k2 = 0; k2 < 8; ++k2) s4[k2 * 128 + tid] = t4[k2 * 128 + tid];
    }
    __syncthreads();

    const float LN2 = 0.6931471805599453f;
    const int len = lengths[bidx];
    const int M   = (len - 1) >> 1;
    const int Kb  = (len - 1) - M;

    U8 A[4][2];
    F4 D[4];
    make_frags(sT, wid, col, g, A, D);

    int need = (wid == 0) ? (M + 1) : Kb;
    int mx = need;
#pragma unroll
    for (int m = 1; m < 64; m <<= 1) mx = max(mx, __shfl_xor(mx, m, 64));
    mx = __builtin_amdgcn_readfirstlane(mx);

    float C = 0.0f, snapC = 0.0f;
    F4 wS[4];
#pragma unroll
    for (int tt = 0; tt < 4; ++tt) wS[tt] = D[tt];

    F4 R0[4], R1[4], R2[4], R3[4], R4_[4], R5[4], R6[4], R7[4];

    // staged tile pointer: slot k of this (dir, blk); +32KB per k step.
    const int k0 = (wid == 0) ? 0 : 1;
    const float* p = stg + ((size_t)(wid * KSLOTS + k0) * 8 + blk) * 1024 + lane * 4;

    LOAD4N(R0, p);              LOAD4N(R1, p + 8192);
    LOAD4N(R2, p + 2*8192);     LOAD4N(R3, p + 3*8192);
    LOAD4N(R4_, p + 4*8192);    LOAD4N(R5, p + 5*8192);
    LOAD4N(R6, p + 6*8192);     LOAD4N(R7, p + 7*8192);
    const float* pn = p + 8*8192;

    const int N_ = (mx + 7) & ~7;     // loads reach slot k0+N_+7 <= 136 < KSLOTS
    if (wid == 0) {
        for (int s = 0; s < N_; s += 8) {
#define FSTEP(QQ, RB, RSF) do { \
            const int t_ = s + (QQ); \
            wait28(); \
            stepfn<true, RSF, true>(D, RB, A, (t_ == M), wS, snapC, C); \
            LOAD4N(RB, pn); pn += 8192; \
        } while (0)
            FSTEP(0, R0, false); FSTEP(1, R1, false); FSTEP(2, R2, false);
            FSTEP(3, R3, false); FSTEP(4, R4_, false); FSTEP(5, R5, false);
            FSTEP(6, R6, false); FSTEP(7, R7, true);
#undef FSTEP
        }
        wait0();
    } else {
        for (int s = 0; s < N_; s += 8) {
#define BSTEP(QQ, RB, RSF) do { \
            const int k_ = s + (QQ) + 1; \
            wait28(); \
            stepfn<true, RSF, false>(D, RB, A, false, wS, snapC, C); \
            if (__ballot(k_ == Kb)) { \
                const bool cc = (k_ == Kb); \
                _Pragma("unroll") \
                for (int tt = 0; tt < 4; ++tt) { \
                    _Pragma("unroll") \
                    for (int r = 0; r < 4; ++r) \
                        wS[tt].f[r] = cc ? D[tt].f[r] : wS[tt].f[r]; \
                } \
                snapC = cc ? C : snapC; \
            } \
            LOAD4N(RB, pn); pn += 8192; \
        } while (0)
            BSTEP(0, R0, false); BSTEP(1, R1, false); BSTEP(2, R2, false);
            BSTEP(3, R3, false); BSTEP(4, R4_, false); BSTEP(5, R5, false);
            BSTEP(6, R6, false); BSTEP(7, R7, true);
#undef BSTEP
        }
        wait0();
    }

    {
        float* dst = (wid == 0) ? sW : sV;
#pragma unroll
        for (int tt = 0; tt < 4; ++tt)
#pragma unroll
            for (int r = 0; r < 4; ++r)
                dst[(16*tt + 4*g + r) * 16 + col] = wS[tt].f[r];
        if (g == 0) { if (wid == 0) sCf[col] = snapC; else sCb[col] = snapC; }
    }
    __syncthreads();
    if (wid == 0) {
        float part = 0.0f;
#pragma unroll
        for (int j = 0; j < 16; ++j) {
            const int n = g * 16 + j;
            part = fmaf(sW[n * 16 + col], sV[n * 16 + col], part);
        }
        part += __shfl_xor(part, 16, 64);
        part += __shfl_xor(part, 32, 64);
        if (g == 0) out[bidx] = sCf[col] + sCb[col] + LN2 * flog2(part);
    }
}

// ---------------- fallback: R6 kernel (direct layout), kept verbatim ----------------
template<bool EUP>
__launch_bounds__(128, 1)
__global__ void crf_fb_old(const float* __restrict__ src,
                           const float* __restrict__ trans,
                           const int* __restrict__ lengths,
                           float* __restrict__ out) {
    const int tid  = threadIdx.x;
    const int wid  = tid >> 6;
    const int lane = tid & 63;
    const int col  = lane & 15;
    const int g    = lane >> 4;
    const int bidx = blockIdx.x * 16 + col;

    __shared__ __align__(16) float sT[N_TAGS * N_TAGS];
    __shared__ __align__(16) float sW[N_TAGS * 16];
    __shared__ __align__(16) float sV[N_TAGS * 16];
    __shared__ float sCf[16], sCb[16];

    {
        const float4* t4 = (const float4*)trans;
        float4* s4 = (float4*)sT;
#pragma unroll
        for (int k2 = 0; k2 < 8; ++k2) s4[k2 * 128 + tid] = t4[k2 * 128 + tid];
    }
    __syncthreads();

    const float LN2 = 0.6931471805599453f;
    const int len = lengths[bidx];
    const int M   = (len - 1) >> 1;
    const int Kb  = (len - 1) - M;

    U8 A[4][2];
    F4 D[4];
    make_frags(sT, wid, col, g, A, D);

    int need = (wid == 0) ? (M + 1) : Kb;
    int mx = need;
#pragma unroll
    for (int m = 1; m < 64; m <<= 1) mx = max(mx, __shfl_xor(mx, m, 64));
    mx = __builtin_amdgcn_readfirstlane(mx);

    const int base = bidx * 64 + 4 * g;
    float C = 0.0f, snapC = 0.0f;
    F4 wS[4];
#pragma unroll
    for (int tt = 0; tt < 4; ++tt) wS[tt] = D[tt];

    F4 R0[4], R1[4], R2[4], R3[4], R4_[4], R5[4], R6[4], R7[4];

    if (wid == 0) {
        const float* pf = src + base;
        LOAD4O(R0, pf);            LOAD4O(R1, pf + BN_);
        LOAD4O(R2, pf + 2*BN_);    LOAD4O(R3, pf + 3*BN_);
        LOAD4O(R4_, pf + 4*BN_);   LOAD4O(R5, pf + 5*BN_);
        LOAD4O(R6, pf + 6*BN_);    LOAD4O(R7, pf + 7*BN_);
        const float* pn = pf + 8 * BN_;
        const int Nf = (mx + 7) & ~7;
        for (int s = 0; s < Nf; s += 8) {
#define FSTEP(QQ, RB, RSF) do { \
            const int t_ = s + (QQ); \
            wait28(); \
            stepfn<EUP, RSF, true>(D, RB, A, (t_ == M), wS, snapC, C); \
            LOAD4O(RB, pn); pn += BN_; \
        } while (0)
            FSTEP(0, R0, false); FSTEP(1, R1, false); FSTEP(2, R2, false);
            FSTEP(3, R3, false); FSTEP(4, R4_, false); FSTEP(5, R5, false);
            FSTEP(6, R6, false); FSTEP(7, R7, true);
#undef FSTEP
        }
        wait0();
    } else {
        const float* pb = src + base;
        {
#define PRIME(RB, q) do { int tq = max(len - 1 - (q), 0); LOAD4O(RB, pb + tq * BN_); } while (0)
            PRIME(R0, 0); PRIME(R1, 1); PRIME(R2, 2); PRIME(R3, 3);
            PRIME(R4_, 4); PRIME(R5, 5); PRIME(R6, 6); PRIME(R7, 7);
#undef PRIME
        }
        int tP = len - 9;
        const int Nb = (mx + 7) & ~7;
        for (int s = 0; s < Nb; s += 8) {
#define BSTEP(QQ, RB, RSF) do { \
            const int k_ = s + (QQ) + 1; \
            wait28(); \
            stepfn<EUP, RSF, false>(D, RB, A, false, wS, snapC, C); \
            if (__ballot(k_ == Kb)) { \
                const bool cc = (k_ == Kb); \
                _Pragma("unroll") \
                for (int tt = 0; tt < 4; ++tt) { \
                    _Pragma("unroll") \
                    for (int r = 0; r < 4; ++r) \
                        wS[tt].f[r] = cc ? D[tt].f[r] : wS[tt].f[r]; \
                } \
                snapC = cc ? C : snapC; \
            } \
            int tc = max(tP, 0); LOAD4O(RB, pb + tc * BN_); tP -= 1; \
        } while (0)
            BSTEP(0, R0, false); BSTEP(1, R1, false); BSTEP(2, R2, false);
            BSTEP(3, R3, false); BSTEP(4, R4_, false); BSTEP(5, R5, false);
            BSTEP(6, R6, false); BSTEP(7, R7, true);
#undef BSTEP
        }
        wait0();
    }

    {
        float* dst = (wid == 0) ? sW : sV;
#pragma unroll
        for (int tt = 0; tt < 4; ++tt)
#pragma unroll
            for (int r = 0; r < 4; ++r)
                dst[(16*tt + 4*g + r) * 16 + col] = wS[tt].f[r];
        if (g == 0) { if (wid == 0) sCf[col] = snapC; else sCb[col] = snapC; }
    }
    __syncthreads();
    if (wid == 0) {
        float part = 0.0f;
#pragma unroll
        for (int j = 0; j < 16; ++j) {
            const int n = g * 16 + j;
            part = fmaf(sW[n * 16 + col], sV[n * 16 + col], part);
        }
        part += __shfl_xor(part, 16, 64);
        part += __shfl_xor(part, 32, 64);
        if (g == 0) out[bidx] = sCf[col] + sCb[col] + LN2 * flog2(part);
    }
}

extern "C" void kernel_launch(void* const* d_in, const int* in_sizes, int n_in,
                              void* d_out, int out_size, void* d_ws, size_t ws_size,
                              hipStream_t stream) {
    const float* unary   = (const float*)d_in[0];
    const float* trans   = (const float*)d_in[1];
    const int*   lengths = (const int*)d_in[2];
    float* out = (float*)d_out;

    const size_t needP = (size_t)2 * KSLOTS * 8 * 1024 * sizeof(float);  // ~17.8 MB
    const size_t needE = (size_t)T_STEPS * B_SIZE * N_TAGS * sizeof(float);
    if (ws_size >= needP) {
        float* stg = (float*)d_ws;
        hipLaunchKernelGGL(prep_kernel, dim3(2 * KSLOTS * 8), dim3(64), 0, stream,
                           unary, lengths, stg);
        hipLaunchKernelGGL(crf_fb_kernel, dim3(B_SIZE / 16), dim3(128), 0, stream,
                           stg, trans, lengths, out);
    } else if (ws_size >= needE) {
        float* eu = (float*)d_ws;
        hipLaunchKernelGGL(expk_kernel, dim3(2048), dim3(256), 0, stream, unary, eu);
        hipLaunchKernelGGL(crf_fb_old<true>, dim3(B_SIZE / 16), dim3(128), 0, stream,
                           eu, trans, lengths, out);
    } else {
        hipLaunchKernelGGL(crf_fb_old<false>, dim3(B_SIZE / 16), dim3(128), 0, stream,
                           unary, trans, lengths, out);
    }
}

// Round 8
// 42.398 us; speedup vs baseline: 1.9225x; 1.0670x over previous
//
#include <hip/hip_runtime.h>

#define T_STEPS 256
#define B_SIZE  128
#define N_TAGS  64
#define BN_     8192      // B*N
#define SEGS    16
#define SEGL    16
#define START_IDX 1
#define END_IDX 2

typedef float  f32x4  __attribute__((ext_vector_type(4)));
typedef float  f32x2  __attribute__((ext_vector_type(2)));
typedef short  bf16x8 __attribute__((ext_vector_type(8)));

union U8 { unsigned u[4]; bf16x8 v; };
union F4 { f32x4 v; f32x2 h[2]; float f[4]; };

__device__ __forceinline__ float fexp2(float x){float r;asm("v_exp_f32 %0, %1":"=v"(r):"v"(x));return r;}
__device__ __forceinline__ float flog2(float x){float r;asm("v_log_f32 %0, %1":"=v"(r):"v"(x));return r;}
__device__ __forceinline__ float frcp(float x){float r;asm("v_rcp_f32 %0, %1":"=v"(r):"v"(x));return r;}
__device__ __forceinline__ unsigned cvtpk(float lo,float hi){unsigned r;asm("v_cvt_pk_bf16_f32 %0, %1, %2":"=v"(r):"v"(lo),"v"(hi));return r;}
__device__ __forceinline__ void swap32(unsigned &a, unsigned &b){asm("v_permlane32_swap_b32 %0, %1":"+v"(a),"+v"(b));}
__device__ __forceinline__ void swap16(unsigned &a, unsigned &b){asm("v_permlane16_swap_b32 %0, %1":"+v"(a),"+v"(b));}
__device__ __forceinline__ f32x2 pkmul(f32x2 a, f32x2 b){f32x2 r;asm("v_pk_mul_f32 %0, %1, %2":"=v"(r):"v"(a),"v"(b));return r;}

#define MFMA16(A, B, C) __builtin_amdgcn_mfma_f32_16x16x32_bf16(A, B, C, 0, 0, 0)

__device__ __forceinline__ void wait24(){ asm volatile("s_waitcnt vmcnt(24)" ::: "memory"); __builtin_amdgcn_sched_barrier(0); }
__device__ __forceinline__ void wait16(){ asm volatile("s_waitcnt vmcnt(16)" ::: "memory"); __builtin_amdgcn_sched_barrier(0); }
__device__ __forceinline__ void wait8 (){ asm volatile("s_waitcnt vmcnt(8)"  ::: "memory"); __builtin_amdgcn_sched_barrier(0); }
__device__ __forceinline__ void wait0 (){ asm volatile("s_waitcnt vmcnt(0)"  ::: "memory"); __builtin_amdgcn_sched_barrier(0); }
__device__ __forceinline__ void wait28(){ asm volatile("s_waitcnt vmcnt(28)" ::: "memory"); __builtin_amdgcn_sched_barrier(0); }

// =========================================================================
// Phase 1: per-(batch, segment) partial matrix product
//   M_{b,s} = prod_{t=s*16+1}^{min(s*16+16, len-1)} diag(exp(u_t)) * exp(trans)
// stored as bf16 MFMA B-fragments (frag (c,cc) at u32 offset (cc*2+c)*4 within
// the lane's 32-u32 block), plus log-scale C_{b,s}.
// =========================================================================
__global__ __launch_bounds__(64, 2)
void crf_seg_kernel(const float* __restrict__ u, const float* __restrict__ trans,
                    const int* __restrict__ lengths,
                    unsigned* __restrict__ Mout, float* __restrict__ Cout) {
    const int bid  = blockIdx.x;
    const int b    = bid & (B_SIZE - 1);
    const int s    = bid >> 7;
    const int lane = threadIdx.x;
    const int col  = lane & 15;
    const int g    = lane >> 4;
    const float K = 1.4426950408889634f, LN2 = 0.6931471805599453f;
    const f32x4 zf = {0.f, 0.f, 0.f, 0.f};

    __shared__ __align__(16) float sT[N_TAGS * N_TAGS];
    {
        const float4* t4 = (const float4*)trans;
        float4* s4 = (float4*)sT;
#pragma unroll
        for (int k = 0; k < 16; ++k) s4[k*64 + lane] = t4[k*64 + lane];
    }
    __syncthreads();

    // A-frags of E = exp(trans): lane holds E[16tt+col][32c+8g+j].
    U8 EA[4][2];
#pragma unroll
    for (int tt = 0; tt < 4; ++tt)
#pragma unroll
        for (int c = 0; c < 2; ++c) {
            const float* p = &sT[(16*tt + col)*64 + 32*c + 8*g];
#pragma unroll
            for (int j2 = 0; j2 < 4; ++j2)
                EA[tt][c].u[j2] = cvtpk(fexp2(p[2*j2]*K), fexp2(p[2*j2+1]*K));
        }

    // P = Identity (bf16 B-frags)
    U8 P[2][4];
#pragma unroll
    for (int c = 0; c < 2; ++c)
#pragma unroll
        for (int cc = 0; cc < 4; ++cc)
#pragma unroll
            for (int m = 0; m < 4; ++m) {
                int k0 = 32*c + 8*g + 2*m, n = 16*cc + col;
                unsigned lo = (k0     == n) ? 0x3F80u : 0u;
                unsigned hi = (k0 + 1 == n) ? 0x3F80u : 0u;
                P[c][cc].u[m] = lo | (hi << 16);
            }

    const int len = lengths[b];
    int n_act = len - 1 - s*SEGL;
    n_act = max(0, min(SEGL, n_act));
    float C = 0.0f;

    if (n_act > 0) {
        const float* ub = u + (size_t)b * 64 + lane;
        const int t0 = s*SEGL + 1;
        float uc = ub[(size_t)t0 * BN_];
        float un = ub[(size_t)min(t0 + 1, T_STEPS - 1) * BN_];
        for (int i = 0; i < n_act; ++i) {
            float eul = fexp2(uc * K);     // lane holds exp(u_t[b][lane])
            uc = un;
            un = ub[(size_t)min(t0 + i + 2, T_STEPS - 1) * BN_];

            // gather per-row eu for this lane's D rows (row = 16tt+4g+r)
            float ev[4][4];
#pragma unroll
            for (int tt = 0; tt < 4; ++tt)
#pragma unroll
                for (int r = 0; r < 4; ++r)
                    ev[tt][r] = __shfl(eul, 16*tt + 4*g + r, 64);

            // D = E * P  (32 MFMA)
            F4 Dt[4][4];
#pragma unroll
            for (int cc = 0; cc < 4; ++cc)
#pragma unroll
                for (int tt = 0; tt < 4; ++tt) {
                    f32x4 acc = MFMA16(EA[tt][0].v, P[0][cc].v, zf);
                    Dt[tt][cc].v = MFMA16(EA[tt][1].v, P[1][cc].v, acc);
                }
            // W = diag(eu) * D
#pragma unroll
            for (int tt = 0; tt < 4; ++tt) {
                f32x2 e01, e23;
                e01[0] = ev[tt][0]; e01[1] = ev[tt][1];
                e23[0] = ev[tt][2]; e23[1] = ev[tt][3];
#pragma unroll
                for (int cc = 0; cc < 4; ++cc) {
                    Dt[tt][cc].h[0] = pkmul(Dt[tt][cc].h[0], e01);
                    Dt[tt][cc].h[1] = pkmul(Dt[tt][cc].h[1], e23);
                }
            }
            // rescale every 8 steps (range safety; growth <= e^~78 between)
            if ((i & 7) == 7) {
                float mm = Dt[0][0].f[0];
#pragma unroll
                for (int tt = 0; tt < 4; ++tt)
#pragma unroll
                    for (int cc = 0; cc < 4; ++cc)
#pragma unroll
                        for (int r = 0; r < 4; ++r)
                            mm = fmaxf(mm, Dt[tt][cc].f[r]);
#pragma unroll
                for (int m2 = 1; m2 < 64; m2 <<= 1)
                    mm = fmaxf(mm, __shfl_xor(mm, m2, 64));
                float inv = frcp(mm);
                C += LN2 * flog2(mm);
                f32x2 iv; iv[0] = inv; iv[1] = inv;
#pragma unroll
                for (int tt = 0; tt < 4; ++tt)
#pragma unroll
                    for (int cc = 0; cc < 4; ++cc) {
                        Dt[tt][cc].h[0] = pkmul(Dt[tt][cc].h[0], iv);
                        Dt[tt][cc].h[1] = pkmul(Dt[tt][cc].h[1], iv);
                    }
            }
            // convert W -> bf16 B-frags (same swap machinery as prior rounds)
#pragma unroll
            for (int cc = 0; cc < 4; ++cc) {
                unsigned p00 = cvtpk(Dt[0][cc].f[0], Dt[0][cc].f[1]);
                unsigned p01 = cvtpk(Dt[0][cc].f[2], Dt[0][cc].f[3]);
                unsigned p10 = cvtpk(Dt[1][cc].f[0], Dt[1][cc].f[1]);
                unsigned p11 = cvtpk(Dt[1][cc].f[2], Dt[1][cc].f[3]);
                unsigned p20 = cvtpk(Dt[2][cc].f[0], Dt[2][cc].f[1]);
                unsigned p21 = cvtpk(Dt[2][cc].f[2], Dt[2][cc].f[3]);
                unsigned p30 = cvtpk(Dt[3][cc].f[0], Dt[3][cc].f[1]);
                unsigned p31 = cvtpk(Dt[3][cc].f[2], Dt[3][cc].f[3]);
                swap32(p00, p10); swap32(p01, p11); swap32(p20, p30); swap32(p21, p31);
                swap16(p00, p10); swap16(p01, p11); swap16(p20, p30); swap16(p21, p31);
                P[0][cc].u[0] = p00; P[0][cc].u[1] = p01; P[0][cc].u[2] = p10; P[0][cc].u[3] = p11;
                P[1][cc].u[0] = p20; P[1][cc].u[1] = p21; P[1][cc].u[2] = p30; P[1][cc].u[3] = p31;
            }
        }
    }

    unsigned* dst = Mout + (size_t)(b*SEGS + s) * 2048 + lane * 32;
#pragma unroll
    for (int cc = 0; cc < 4; ++cc)
#pragma unroll
        for (int c = 0; c < 2; ++c) {
            uint4 q;
            q.x = P[c][cc].u[0]; q.y = P[c][cc].u[1];
            q.z = P[c][cc].u[2]; q.w = P[c][cc].u[3];
            *(uint4*)(dst + (cc*2 + c)*4) = q;
        }
    if (lane == 0) Cout[b*SEGS + s] = C;
}

// =========================================================================
// Phase 2: per batch, fold 16 segment matrices with a row-vector:
//   a <- a * M_s   (s = 15..0),   Z = sum_n a[n] * w0[n],  w0 = exp(u0 + tStart)
// Broadcast-A MFMA: A[row][k] = a[k] for all rows -> every lane holds the full
// result; next A-frag built with in-group shuffles (no LDS).
// =========================================================================
#define MLOAD(SL, SEG) do { const unsigned* _mp = mb + (size_t)(SEG) * 2048; \
    asm volatile("global_load_dwordx4 %0, %1, off"            : "=v"(SL[0].v) : "v"(_mp)); \
    asm volatile("global_load_dwordx4 %0, %1, off offset:16"  : "=v"(SL[1].v) : "v"(_mp)); \
    asm volatile("global_load_dwordx4 %0, %1, off offset:32"  : "=v"(SL[2].v) : "v"(_mp)); \
    asm volatile("global_load_dwordx4 %0, %1, off offset:48"  : "=v"(SL[3].v) : "v"(_mp)); \
    asm volatile("global_load_dwordx4 %0, %1, off offset:64"  : "=v"(SL[4].v) : "v"(_mp)); \
    asm volatile("global_load_dwordx4 %0, %1, off offset:80"  : "=v"(SL[5].v) : "v"(_mp)); \
    asm volatile("global_load_dwordx4 %0, %1, off offset:96"  : "=v"(SL[6].v) : "v"(_mp)); \
    asm volatile("global_load_dwordx4 %0, %1, off offset:112" : "=v"(SL[7].v) : "v"(_mp)); \
} while (0)

#define PSTEP(WN, SL, LD) do { \
    wait##WN(); \
    U8 Af0, Af1; \
    { float vs = (g < 2) ? a0 : a1; \
      float f0=__shfl(vs,sbase+0,64), f1=__shfl(vs,sbase+1,64); \
      float f2=__shfl(vs,sbase+2,64), f3=__shfl(vs,sbase+3,64); \
      float f4=__shfl(vs,sbase+4,64), f5=__shfl(vs,sbase+5,64); \
      float f6=__shfl(vs,sbase+6,64), f7=__shfl(vs,sbase+7,64); \
      Af0.u[0]=cvtpk(f0,f1); Af0.u[1]=cvtpk(f2,f3); Af0.u[2]=cvtpk(f4,f5); Af0.u[3]=cvtpk(f6,f7); } \
    { float vs = (g < 2) ? a2 : a3; \
      float f0=__shfl(vs,sbase+0,64), f1=__shfl(vs,sbase+1,64); \
      float f2=__shfl(vs,sbase+2,64), f3=__shfl(vs,sbase+3,64); \
      float f4=__shfl(vs,sbase+4,64), f5=__shfl(vs,sbase+5,64); \
      float f6=__shfl(vs,sbase+6,64), f7=__shfl(vs,sbase+7,64); \
      Af1.u[0]=cvtpk(f0,f1); Af1.u[1]=cvtpk(f2,f3); Af1.u[2]=cvtpk(f4,f5); Af1.u[3]=cvtpk(f6,f7); } \
    f32x4 q0 = MFMA16(Af0.v, SL[0].v, zf); q0 = MFMA16(Af1.v, SL[1].v, q0); \
    f32x4 q1 = MFMA16(Af0.v, SL[2].v, zf); q1 = MFMA16(Af1.v, SL[3].v, q1); \
    f32x4 q2 = MFMA16(Af0.v, SL[4].v, zf); q2 = MFMA16(Af1.v, SL[5].v, q2); \
    f32x4 q3 = MFMA16(Af0.v, SL[6].v, zf); q3 = MFMA16(Af1.v, SL[7].v, q3); \
    float n0 = q0[0], n1 = q1[0], n2 = q2[0], n3 = q3[0]; \
    float mm = fmaxf(fmaxf(n0, n1), fmaxf(n2, n3)); \
    mm = fmaxf(mm, __shfl_xor(mm, 1, 64)); mm = fmaxf(mm, __shfl_xor(mm, 2, 64)); \
    mm = fmaxf(mm, __shfl_xor(mm, 4, 64)); mm = fmaxf(mm, __shfl_xor(mm, 8, 64)); \
    float inv = frcp(mm); C2 += LN2 * flog2(mm); \
    a0 = n0 * inv; a1 = n1 * inv; a2 = n2 * inv; a3 = n3 * inv; \
    if ((LD) >= 0) { MLOAD(SL, LD); } \
} while (0)

__global__ __launch_bounds__(64, 1)
void crf_comb_kernel(const float* __restrict__ u, const float* __restrict__ trans,
                     const unsigned* __restrict__ Mbuf, const float* __restrict__ Cseg,
                     float* __restrict__ out) {
    const int b    = blockIdx.x;
    const int lane = threadIdx.x;
    const int col  = lane & 15;
    const int g    = lane >> 4;
    const float K = 1.4426950408889634f, LN2 = 0.6931471805599453f;
    const f32x4 zf = {0.f, 0.f, 0.f, 0.f};

    // a = f = exp(trans[END][n]); lane holds a[16cc+col] in a{cc}
    float a0 = fexp2(trans[END_IDX*64 + 0  + col] * K);
    float a1 = fexp2(trans[END_IDX*64 + 16 + col] * K);
    float a2 = fexp2(trans[END_IDX*64 + 32 + col] * K);
    float a3 = fexp2(trans[END_IDX*64 + 48 + col] * K);

    float ct = 0.0f;
#pragma unroll
    for (int k = 0; k < SEGS; ++k) ct += Cseg[b*SEGS + k];

    const int sbase = (lane & 48) | ((g & 1) << 3);
    const unsigned* mb = Mbuf + (size_t)b * SEGS * 2048 + lane * 32;

    U8 MP0[8], MP1[8], MP2[8], MP3[8];
    MLOAD(MP0, 15); MLOAD(MP1, 14); MLOAD(MP2, 13); MLOAD(MP3, 12);

    float C2 = 0.0f;
    PSTEP(24, MP0, 11); PSTEP(24, MP1, 10); PSTEP(24, MP2,  9); PSTEP(24, MP3,  8);
    PSTEP(24, MP0,  7); PSTEP(24, MP1,  6); PSTEP(24, MP2,  5); PSTEP(24, MP3,  4);
    PSTEP(24, MP0,  3); PSTEP(24, MP1,  2); PSTEP(24, MP2,  1); PSTEP(24, MP3,  0);
    PSTEP(24, MP0, -1); PSTEP(16, MP1, -1); PSTEP(8,  MP2, -1); PSTEP(0,  MP3, -1);

    float part = 0.0f;
#pragma unroll
    for (int cc = 0; cc < 4; ++cc) {
        int n = 16*cc + col;
        float w0 = fexp2((u[(size_t)b*64 + n] + trans[n*64 + START_IDX]) * K);
        float av = (cc == 0) ? a0 : ((cc == 1) ? a1 : ((cc == 2) ? a2 : a3));
        part = fmaf(av, w0, part);
    }
    part += __shfl_xor(part, 1, 64);
    part += __shfl_xor(part, 2, 64);
    part += __shfl_xor(part, 4, 64);
    part += __shfl_xor(part, 8, 64);
    if (lane == 0) out[b] = ct + C2 + LN2 * flog2(part);
}

// =========================================================================
// Fallback (ws too small): R6 fwd/bwd serial kernel, direct layout.
// =========================================================================
#define LOAD4O(RB, PTR) do { const float* _p = (PTR); \
    asm volatile("global_load_dwordx4 %0, %1, off"            : "=v"(RB[0].v) : "v"(_p)); \
    asm volatile("global_load_dwordx4 %0, %1, off offset:64"  : "=v"(RB[1].v) : "v"(_p)); \
    asm volatile("global_load_dwordx4 %0, %1, off offset:128" : "=v"(RB[2].v) : "v"(_p)); \
    asm volatile("global_load_dwordx4 %0, %1, off offset:192" : "=v"(RB[3].v) : "v"(_p)); \
} while (0)

template<bool EUP, bool RS, bool SNAPW>
__device__ __forceinline__ void stepfn(F4 (&D)[4], F4 (&UB)[4], const U8 (&A)[4][2],
                                       bool ccw, F4 (&wS)[4], float &snapC, float &C) {
    const float K = 1.4426950408889634f, LN2 = 0.6931471805599453f;
    const f32x4 zf = {0.f, 0.f, 0.f, 0.f};
    F4 W[4];
#pragma unroll
    for (int tt = 0; tt < 4; ++tt) {
        if (EUP) {
            W[tt].h[0] = pkmul(D[tt].h[0], UB[tt].h[0]);
            W[tt].h[1] = pkmul(D[tt].h[1], UB[tt].h[1]);
        } else {
#pragma unroll
            for (int r = 0; r < 4; ++r) W[tt].f[r] = D[tt].f[r] * fexp2(UB[tt].f[r] * K);
        }
    }
    if (RS) {
        float m0 = fmaxf(fmaxf(W[0].f[0], W[0].f[1]), fmaxf(W[0].f[2], W[0].f[3]));
        float m1 = fmaxf(fmaxf(W[1].f[0], W[1].f[1]), fmaxf(W[1].f[2], W[1].f[3]));
        float m2 = fmaxf(fmaxf(W[2].f[0], W[2].f[1]), fmaxf(W[2].f[2], W[2].f[3]));
        float m3 = fmaxf(fmaxf(W[3].f[0], W[3].f[1]), fmaxf(W[3].f[2], W[3].f[3]));
        float mm = fmaxf(fmaxf(m0, m1), fmaxf(m2, m3));
        mm = fmaxf(mm, __shfl_xor(mm, 16, 64));
        mm = fmaxf(mm, __shfl_xor(mm, 32, 64));
        float inv = frcp(mm);
        C += LN2 * flog2(mm);
        f32x2 iv; iv[0] = inv; iv[1] = inv;
#pragma unroll
        for (int tt = 0; tt < 4; ++tt) {
            W[tt].h[0] = pkmul(W[tt].h[0], iv);
            W[tt].h[1] = pkmul(W[tt].h[1], iv);
        }
    }
    if (SNAPW) {
        if (__ballot(ccw)) {
#pragma unroll
            for (int tt = 0; tt < 4; ++tt)
#pragma unroll
                for (int r = 0; r < 4; ++r)
                    wS[tt].f[r] = ccw ? W[tt].f[r] : wS[tt].f[r];
            snapC = ccw ? C : snapC;
        }
    }
    unsigned p00 = cvtpk(W[0].f[0], W[0].f[1]), p01 = cvtpk(W[0].f[2], W[0].f[3]);
    unsigned p10 = cvtpk(W[1].f[0], W[1].f[1]), p11 = cvtpk(W[1].f[2], W[1].f[3]);
    unsigned p20 = cvtpk(W[2].f[0], W[2].f[1]), p21 = cvtpk(W[2].f[2], W[2].f[3]);
    unsigned p30 = cvtpk(W[3].f[0], W[3].f[1]), p31 = cvtpk(W[3].f[2], W[3].f[3]);
    swap32(p00, p10); swap32(p01, p11); swap32(p20, p30); swap32(p21, p31);
    swap16(p00, p10); swap16(p01, p11); swap16(p20, p30); swap16(p21, p31);
    U8 b0, b1;
    b0.u[0] = p00; b0.u[1] = p01; b0.u[2] = p10; b0.u[3] = p11;
    b1.u[0] = p20; b1.u[1] = p21; b1.u[2] = p30; b1.u[3] = p31;
#pragma unroll
    for (int tt = 0; tt < 4; ++tt) {
        f32x4 acc = MFMA16(A[tt][0].v, b0.v, zf);
        D[tt].v   = MFMA16(A[tt][1].v, b1.v, acc);
    }
}

__device__ __forceinline__ void make_frags(const float* sT, int wid, int col, int g,
                                           U8 (&A)[4][2], F4 (&D)[4]) {
    const float K = 1.4426950408889634f;
    if (wid == 0) {
#pragma unroll
        for (int tt = 0; tt < 4; ++tt)
#pragma unroll
            for (int c = 0; c < 2; ++c) {
                const float* p = &sT[(16*tt + col)*64 + 32*c + 8*g];
#pragma unroll
                for (int j2 = 0; j2 < 4; ++j2)
                    A[tt][c].u[j2] = cvtpk(fexp2(p[2*j2]*K), fexp2(p[2*j2+1]*K));
            }
#pragma unroll
        for (int tt = 0; tt < 4; ++tt)
#pragma unroll
            for (int r = 0; r < 4; ++r)
                D[tt].f[r] = fexp2(sT[(16*tt + 4*g + r)*64 + START_IDX] * K);
    } else {
#pragma unroll
        for (int tt = 0; tt < 4; ++tt)
#pragma unroll
            for (int c = 0; c < 2; ++c) {
#pragma unroll
                for (int j2 = 0; j2 < 4; ++j2) {
                    const int a0 = 32*c + 8*g + 2*j2;
                    A[tt][c].u[j2] = cvtpk(fexp2(sT[a0*64 + 16*tt + col] * K),
                                           fexp2(sT[(a0+1)*64 + 16*tt + col] * K));
                }
            }
#pragma unroll
        for (int tt = 0; tt < 4; ++tt)
#pragma unroll
            for (int r = 0; r < 4; ++r)
                D[tt].f[r] = fexp2(sT[END_IDX*64 + 16*tt + 4*g + r] * K);
    }
}

__launch_bounds__(128, 1)
__global__ void crf_fb_old(const float* __restrict__ src,
                           const float* __restrict__ trans,
                           const int* __restrict__ lengths,
                           float* __restrict__ out) {
    const int tid  = threadIdx.x;
    const int wid  = tid >> 6;
    const int lane = tid & 63;
    const int col  = lane & 15;
    const int g    = lane >> 4;
    const int bidx = blockIdx.x * 16 + col;

    __shared__ __align__(16) float sT[N_TAGS * N_TAGS];
    __shared__ __align__(16) float sW[N_TAGS * 16];
    __shared__ __align__(16) float sV[N_TAGS * 16];
    __shared__ float sCf[16], sCb[16];

    {
        const float4* t4 = (const float4*)trans;
        float4* s4 = (float4*)sT;
#pragma unroll
        for (int k2 = 0; k2 < 8; ++k2) s4[k2 * 128 + tid] = t4[k2 * 128 + tid];
    }
    __syncthreads();

    const float LN2 = 0.6931471805599453f;
    const int len = lengths[bidx];
    const int M   = (len - 1) >> 1;
    const int Kb  = (len - 1) - M;

    U8 A[4][2];
    F4 D[4];
    make_frags(sT, wid, col, g, A, D);

    int need = (wid == 0) ? (M + 1) : Kb;
    int mx = need;
#pragma unroll
    for (int m = 1; m < 64; m <<= 1) mx = max(mx, __shfl_xor(mx, m, 64));
    mx = __builtin_amdgcn_readfirstlane(mx);

    const int base = bidx * 64 + 4 * g;
    float C = 0.0f, snapC = 0.0f;
    F4 wS[4];
#pragma unroll
    for (int tt = 0; tt < 4; ++tt) wS[tt] = D[tt];

    F4 R0[4], R1[4], R2[4], R3[4], R4_[4], R5[4], R6[4], R7[4];

    if (wid == 0) {
        const float* pf = src + base;
        LOAD4O(R0, pf);            LOAD4O(R1, pf + BN_);
        LOAD4O(R2, pf + 2*BN_);    LOAD4O(R3, pf + 3*BN_);
        LOAD4O(R4_, pf + 4*BN_);   LOAD4O(R5, pf + 5*BN_);
        LOAD4O(R6, pf + 6*BN_);    LOAD4O(R7, pf + 7*BN_);
        const float* pn = pf + 8 * BN_;
        const int Nf = (mx + 7) & ~7;
        for (int s = 0; s < Nf; s += 8) {
#define FSTEP(QQ, RB, RSF) do { \
            const int t_ = s + (QQ); \
            wait28(); \
            stepfn<false, RSF, true>(D, RB, A, (t_ == M), wS, snapC, C); \
            LOAD4O(RB, pn); pn += BN_; \
        } while (0)
            FSTEP(0, R0, false); FSTEP(1, R1, false); FSTEP(2, R2, false);
            FSTEP(3, R3, false); FSTEP(4, R4_, false); FSTEP(5, R5, false);
            FSTEP(6, R6, false); FSTEP(7, R7, true);
#undef FSTEP
        }
        wait0();
    } else {
        const float* pb = src + base;
        {
#define PRIME(RB, q) do { int tq = max(len - 1 - (q), 0); LOAD4O(RB, pb + tq * BN_); } while (0)
            PRIME(R0, 0); PRIME(R1, 1); PRIME(R2, 2); PRIME(R3, 3);
            PRIME(R4_, 4); PRIME(R5, 5); PRIME(R6, 6); PRIME(R7, 7);
#undef PRIME
        }
        int tP = len - 9;
        const int Nb = (mx + 7) & ~7;
        for (int s = 0; s < Nb; s += 8) {
#define BSTEP(QQ, RB, RSF) do { \
            const int k_ = s + (QQ) + 1; \
            wait28(); \
            stepfn<false, RSF, false>(D, RB, A, false, wS, snapC, C); \
            if (__ballot(k_ == Kb)) { \
                const bool cc = (k_ == Kb); \
                _Pragma("unroll") \
                for (int tt = 0; tt < 4; ++tt) { \
                    _Pragma("unroll") \
                    for (int r = 0; r < 4; ++r) \
                        wS[tt].f[r] = cc ? D[tt].f[r] : wS[tt].f[r]; \
                } \
                snapC = cc ? C : snapC; \
            } \
            int tc = max(tP, 0); LOAD4O(RB, pb + tc * BN_); tP -= 1; \
        } while (0)
            BSTEP(0, R0, false); BSTEP(1, R1, false); BSTEP(2, R2, false);
            BSTEP(3, R3, false); BSTEP(4, R4_, false); BSTEP(5, R5, false);
            BSTEP(6, R6, false); BSTEP(7, R7, true);
#undef BSTEP
        }
        wait0();
    }

    {
        float* dst = (wid == 0) ? sW : sV;
#pragma unroll
        for (int tt = 0; tt < 4; ++tt)
#pragma unroll
            for (int r = 0; r < 4; ++r)
                dst[(16*tt + 4*g + r) * 16 + col] = wS[tt].f[r];
        if (g == 0) { if (wid == 0) sCf[col] = snapC; else sCb[col] = snapC; }
    }
    __syncthreads();
    if (wid == 0) {
        float part = 0.0f;
#pragma unroll
        for (int j = 0; j < 16; ++j) {
            const int n = g * 16 + j;
            part = fmaf(sW[n * 16 + col], sV[n * 16 + col], part);
        }
        part += __shfl_xor(part, 16, 64);
        part += __shfl_xor(part, 32, 64);
        if (g == 0) out[bidx] = sCf[col] + sCb[col] + LN2 * flog2(part);
    }
}

extern "C" void kernel_launch(void* const* d_in, const int* in_sizes, int n_in,
                              void* d_out, int out_size, void* d_ws, size_t ws_size,
                              hipStream_t stream) {
    const float* unary   = (const float*)d_in[0];
    const float* trans   = (const float*)d_in[1];
    const int*   lengths = (const int*)d_in[2];
    float* out = (float*)d_out;

    const size_t mcount = (size_t)B_SIZE * SEGS * 2048;       // u32 elements
    const size_t need   = mcount * 4 + (size_t)B_SIZE * SEGS * 4;
    if (ws_size >= need) {
        unsigned* Mbuf = (unsigned*)d_ws;
        float* Cseg = (float*)((unsigned*)d_ws + mcount);
        hipLaunchKernelGGL(crf_seg_kernel, dim3(B_SIZE * SEGS), dim3(64), 0, stream,
                           unary, trans, lengths, Mbuf, Cseg);
        hipLaunchKernelGGL(crf_comb_kernel, dim3(B_SIZE), dim3(64), 0, stream,
                           unary, trans, Mbuf, Cseg, out);
    } else {
        hipLaunchKernelGGL(crf_fb_old, dim3(B_SIZE / 16), dim3(128), 0, stream,
                           unary, trans, lengths, out);
    }
}

// Round 9
// 39.664 us; speedup vs baseline: 2.0550x; 1.0689x over previous
//
#include <hip/hip_runtime.h>

#define T_STEPS 256
#define B_SIZE  128
#define N_TAGS  64
#define BN_     8192      // B*N
#define SEGS    16
#define SEGL    16
#define START_IDX 1
#define END_IDX 2

typedef float  f32x4  __attribute__((ext_vector_type(4)));
typedef float  f32x2  __attribute__((ext_vector_type(2)));
typedef short  bf16x8 __attribute__((ext_vector_type(8)));

union U8 { unsigned u[4]; bf16x8 v; };
union F4 { f32x4 v; f32x2 h[2]; float f[4]; };

__device__ __forceinline__ float fexp2(float x){float r;asm("v_exp_f32 %0, %1":"=v"(r):"v"(x));return r;}
__device__ __forceinline__ float flog2(float x){float r;asm("v_log_f32 %0, %1":"=v"(r):"v"(x));return r;}
__device__ __forceinline__ float frcp(float x){float r;asm("v_rcp_f32 %0, %1":"=v"(r):"v"(x));return r;}
__device__ __forceinline__ unsigned cvtpk(float lo,float hi){unsigned r;asm("v_cvt_pk_bf16_f32 %0, %1, %2":"=v"(r):"v"(lo),"v"(hi));return r;}
__device__ __forceinline__ void swap32(unsigned &a, unsigned &b){asm("v_permlane32_swap_b32 %0, %1":"+v"(a),"+v"(b));}
__device__ __forceinline__ void swap16(unsigned &a, unsigned &b){asm("v_permlane16_swap_b32 %0, %1":"+v"(a),"+v"(b));}
__device__ __forceinline__ f32x2 pkmul(f32x2 a, f32x2 b){f32x2 r;asm("v_pk_mul_f32 %0, %1, %2":"=v"(r):"v"(a),"v"(b));return r;}

#define MFMA16(A, B, C) __builtin_amdgcn_mfma_f32_16x16x32_bf16(A, B, C, 0, 0, 0)

__device__ __forceinline__ void wait24(){ asm volatile("s_waitcnt vmcnt(24)" ::: "memory"); __builtin_amdgcn_sched_barrier(0); }
__device__ __forceinline__ void wait16(){ asm volatile("s_waitcnt vmcnt(16)" ::: "memory"); __builtin_amdgcn_sched_barrier(0); }
__device__ __forceinline__ void wait8 (){ asm volatile("s_waitcnt vmcnt(8)"  ::: "memory"); __builtin_amdgcn_sched_barrier(0); }
__device__ __forceinline__ void wait0 (){ asm volatile("s_waitcnt vmcnt(0)"  ::: "memory"); __builtin_amdgcn_sched_barrier(0); }
__device__ __forceinline__ void wait28(){ asm volatile("s_waitcnt vmcnt(28)" ::: "memory"); __builtin_amdgcn_sched_barrier(0); }

// ---------------- shared macro blocks (operate on local vars) ----------------
#define IDP() do { _Pragma("unroll") \
  for (int c=0;c<2;++c) { _Pragma("unroll") \
    for (int cc=0;cc<4;++cc) { _Pragma("unroll") \
      for (int m=0;m<4;++m) { \
        int k0 = 32*c + 8*g + 2*m, n = 16*cc + col; \
        unsigned lo = (k0==n)?0x3F80u:0u, hi=(k0+1==n)?0x3F80u:0u; \
        P[c][cc].u[m] = lo | (hi<<16); } } } } while(0)

#define EVG() do { _Pragma("unroll") \
  for (int tt=0;tt<4;++tt) { _Pragma("unroll") \
    for (int r=0;r<4;++r) ev[tt][r] = __shfl(eul, 16*tt + 4*g + r, 64); } } while(0)

#define EVSCALE() do { _Pragma("unroll") \
  for (int tt=0;tt<4;++tt) { f32x2 e01,e23; \
    e01[0]=ev[tt][0]; e01[1]=ev[tt][1]; e23[0]=ev[tt][2]; e23[1]=ev[tt][3]; \
    _Pragma("unroll") for (int cc=0;cc<4;++cc) { \
      Dt[tt][cc].h[0]=pkmul(Dt[tt][cc].h[0],e01); \
      Dt[tt][cc].h[1]=pkmul(Dt[tt][cc].h[1],e23); } } } while(0)

#define RESC() do { float mm = Dt[0][0].f[0]; \
  _Pragma("unroll") for (int tt=0;tt<4;++tt) { _Pragma("unroll") for (int cc=0;cc<4;++cc) { \
    _Pragma("unroll") for (int r=0;r<4;++r) mm = fmaxf(mm, Dt[tt][cc].f[r]); } } \
  _Pragma("unroll") for (int m2=1;m2<64;m2<<=1) mm = fmaxf(mm, __shfl_xor(mm,m2,64)); \
  float inv = frcp(mm); C += LN2*flog2(mm); \
  f32x2 iv; iv[0]=inv; iv[1]=inv; \
  _Pragma("unroll") for (int tt=0;tt<4;++tt) { _Pragma("unroll") for (int cc=0;cc<4;++cc) { \
    Dt[tt][cc].h[0]=pkmul(Dt[tt][cc].h[0],iv); Dt[tt][cc].h[1]=pkmul(Dt[tt][cc].h[1],iv); } } } while(0)

#define CVTP() do { _Pragma("unroll") \
  for (int cc=0;cc<4;++cc) { \
    unsigned p00 = cvtpk(Dt[0][cc].f[0], Dt[0][cc].f[1]); \
    unsigned p01 = cvtpk(Dt[0][cc].f[2], Dt[0][cc].f[3]); \
    unsigned p10 = cvtpk(Dt[1][cc].f[0], Dt[1][cc].f[1]); \
    unsigned p11 = cvtpk(Dt[1][cc].f[2], Dt[1][cc].f[3]); \
    unsigned p20 = cvtpk(Dt[2][cc].f[0], Dt[2][cc].f[1]); \
    unsigned p21 = cvtpk(Dt[2][cc].f[2], Dt[2][cc].f[3]); \
    unsigned p30 = cvtpk(Dt[3][cc].f[0], Dt[3][cc].f[1]); \
    unsigned p31 = cvtpk(Dt[3][cc].f[2], Dt[3][cc].f[3]); \
    swap32(p00, p10); swap32(p01, p11); swap32(p20, p30); swap32(p21, p31); \
    swap16(p00, p10); swap16(p01, p11); swap16(p20, p30); swap16(p21, p31); \
    P[0][cc].u[0]=p00; P[0][cc].u[1]=p01; P[0][cc].u[2]=p10; P[0][cc].u[3]=p11; \
    P[1][cc].u[0]=p20; P[1][cc].u[1]=p21; P[1][cc].u[2]=p30; P[1][cc].u[3]=p31; } } while(0)

#define MFMAB() do { _Pragma("unroll") \
  for (int cc=0;cc<4;++cc) { _Pragma("unroll") \
    for (int tt=0;tt<4;++tt) { \
      f32x4 acc = MFMA16(EA[tt][0].v, P[0][cc].v, zf); \
      Dt[tt][cc].v = MFMA16(EA[tt][1].v, P[1][cc].v, acc); } } } while(0)

#define STOREP() do { _Pragma("unroll") \
  for (int cc=0;cc<4;++cc) { _Pragma("unroll") \
    for (int c=0;c<2;++c) { \
      uint4 q; q.x=P[c][cc].u[0]; q.y=P[c][cc].u[1]; q.z=P[c][cc].u[2]; q.w=P[c][cc].u[3]; \
      *(uint4*)(dst + (cc*2+c)*256) = q; } } } while(0)

// =========================================================================
// Phase 1: per-(batch, segment) partial products.
//   s >= 8 (back half):  M_s   = prod_{t asc} diag(eu_t) E          (B-frags)
//   s <  8 (front half): Q_s = M_s^T = prod: E^T diag(eu_t), t desc  (B-frags)
// Coalesced layout: word (fp, lane, m) at  mslot*2048 + fp*256 + lane*4 + m.
// =========================================================================
__global__ __launch_bounds__(64, 2)
void crf_seg_kernel(const float* __restrict__ u, const float* __restrict__ trans,
                    const int* __restrict__ lengths,
                    unsigned* __restrict__ Mout, float* __restrict__ Cout) {
    const int bid  = blockIdx.x;
    const int b    = bid & (B_SIZE - 1);
    const int s    = bid >> 7;
    const int lane = threadIdx.x;
    const int col  = lane & 15;
    const int g    = lane >> 4;
    const float K = 1.4426950408889634f, LN2 = 0.6931471805599453f;
    const f32x4 zf = {0.f, 0.f, 0.f, 0.f};

    const int len = lengths[b];
    int n_act = len - 1 - s*SEGL;
    n_act = max(0, min(SEGL, n_act));
    unsigned* dst = Mout + (size_t)(b*SEGS + s) * 2048 + lane * 4;

    U8 P[2][4];
    if (n_act == 0) {           // identity segment: no staging, no MFMA
        IDP();
        STOREP();
        if (lane == 0) Cout[b*SEGS + s] = 0.0f;
        return;
    }

    __shared__ __align__(16) float sT[N_TAGS * N_TAGS];
    {
        const float4* t4 = (const float4*)trans;
        float4* s4 = (float4*)sT;
#pragma unroll
        for (int k = 0; k < 16; ++k) s4[k*64 + lane] = t4[k*64 + lane];
    }
    __syncthreads();

    const bool front = (s < 8);
    U8 EA[4][2];
    if (!front) {
        // A-frags of E: lane holds E[16tt+col][32c+8g+j]
#pragma unroll
        for (int tt = 0; tt < 4; ++tt) {
#pragma unroll
            for (int c = 0; c < 2; ++c) {
                const float* p = &sT[(16*tt + col)*64 + 32*c + 8*g];
#pragma unroll
                for (int j2 = 0; j2 < 4; ++j2)
                    EA[tt][c].u[j2] = cvtpk(fexp2(p[2*j2]*K), fexp2(p[2*j2+1]*K));
            }
        }
    } else {
        // A-frags of E^T: lane holds E[32c+8g+j][16tt+col]
#pragma unroll
        for (int tt = 0; tt < 4; ++tt) {
#pragma unroll
            for (int c = 0; c < 2; ++c) {
#pragma unroll
                for (int j2 = 0; j2 < 4; ++j2) {
                    const int a0 = 32*c + 8*g + 2*j2;
                    EA[tt][c].u[j2] = cvtpk(fexp2(sT[a0*64 + 16*tt + col] * K),
                                            fexp2(sT[(a0+1)*64 + 16*tt + col] * K));
                }
            }
        }
    }

    F4 Dt[4][4];
    float C = 0.0f;
    float ev[4][4];
    const float* ub = u + (size_t)b * 64 + lane;

    if (!front) {
        IDP();                                   // P = I
        const int t0 = 16*s + 1;
        float uc = ub[(size_t)t0 * BN_];
        float un = ub[(size_t)min(t0 + 1, T_STEPS - 1) * BN_];
        for (int i = 0; i < n_act; ++i) {
            float eul = fexp2(uc * K);
            uc = un; un = ub[(size_t)min(t0 + i + 2, T_STEPS - 1) * BN_];
            EVG();
            MFMAB();                             // Dt = E * P
            EVSCALE();                           // Dt = diag(eu) * Dt
            if ((i & 7) == 7) RESC();
            CVTP();                              // P = bf16(Dt)
        }
    } else {
        // Dt = I (f32, D-layout)
#pragma unroll
        for (int tt = 0; tt < 4; ++tt) {
#pragma unroll
            for (int cc = 0; cc < 4; ++cc) {
#pragma unroll
                for (int r = 0; r < 4; ++r)
                    Dt[tt][cc].f[r] = (tt == cc && 4*g + r == col) ? 1.0f : 0.0f;
            }
        }
        const int th = 16*s + n_act;             // highest active t, descending
        float uc = ub[(size_t)th * BN_];
        float un = ub[(size_t)max(th - 1, 0) * BN_];
        for (int i = 0; i < n_act; ++i) {
            float eul = fexp2(uc * K);
            uc = un; un = ub[(size_t)max(th - i - 2, 0) * BN_];
            EVG();
            EVSCALE();                           // Dt = diag(eu_t) * Dt
            if ((i & 7) == 7) RESC();
            CVTP();                              // P = bf16(Dt)
            MFMAB();                             // Dt = E^T * P
        }
        CVTP();                                  // final convert
    }

    STOREP();
    if (lane == 0) Cout[b*SEGS + s] = C;
}

// =========================================================================
// Phase 2: two-wave fold per batch (8 serial steps each):
//   wave0 (front): x^T = w0^T * Q0 * Q1 * ... * Q7
//   wave1 (back):  a   = f * M15 * M14 * ... * M8
//   Z = sum_n a[n] * x[n]  (plus accumulated log-scales)
// =========================================================================
#define MLOAD(SL, SEG) do { \
    const unsigned* _mp = mbase + (size_t)(SEG) * 2048; \
    const unsigned* _mq = _mp + 1024; \
    asm volatile("global_load_dwordx4 %0, %1, off"             : "=v"(SL[0].v) : "v"(_mp)); \
    asm volatile("global_load_dwordx4 %0, %1, off offset:1024" : "=v"(SL[1].v) : "v"(_mp)); \
    asm volatile("global_load_dwordx4 %0, %1, off offset:2048" : "=v"(SL[2].v) : "v"(_mp)); \
    asm volatile("global_load_dwordx4 %0, %1, off offset:3072" : "=v"(SL[3].v) : "v"(_mp)); \
    asm volatile("global_load_dwordx4 %0, %1, off"             : "=v"(SL[4].v) : "v"(_mq)); \
    asm volatile("global_load_dwordx4 %0, %1, off offset:1024" : "=v"(SL[5].v) : "v"(_mq)); \
    asm volatile("global_load_dwordx4 %0, %1, off offset:2048" : "=v"(SL[6].v) : "v"(_mq)); \
    asm volatile("global_load_dwordx4 %0, %1, off offset:3072" : "=v"(SL[7].v) : "v"(_mq)); \
} while (0)

#define PSTEP(WN, SL, LD) do { \
    wait##WN(); \
    U8 Af0, Af1; \
    { float vs = (g < 2) ? a0 : a1; \
      float f0=__shfl(vs,sbase+0,64), f1=__shfl(vs,sbase+1,64); \
      float f2=__shfl(vs,sbase+2,64), f3=__shfl(vs,sbase+3,64); \
      float f4=__shfl(vs,sbase+4,64), f5=__shfl(vs,sbase+5,64); \
      float f6=__shfl(vs,sbase+6,64), f7=__shfl(vs,sbase+7,64); \
      Af0.u[0]=cvtpk(f0,f1); Af0.u[1]=cvtpk(f2,f3); Af0.u[2]=cvtpk(f4,f5); Af0.u[3]=cvtpk(f6,f7); } \
    { float vs = (g < 2) ? a2 : a3; \
      float f0=__shfl(vs,sbase+0,64), f1=__shfl(vs,sbase+1,64); \
      float f2=__shfl(vs,sbase+2,64), f3=__shfl(vs,sbase+3,64); \
      float f4=__shfl(vs,sbase+4,64), f5=__shfl(vs,sbase+5,64); \
      float f6=__shfl(vs,sbase+6,64), f7=__shfl(vs,sbase+7,64); \
      Af1.u[0]=cvtpk(f0,f1); Af1.u[1]=cvtpk(f2,f3); Af1.u[2]=cvtpk(f4,f5); Af1.u[3]=cvtpk(f6,f7); } \
    f32x4 q0 = MFMA16(Af0.v, SL[0].v, zf); q0 = MFMA16(Af1.v, SL[1].v, q0); \
    f32x4 q1 = MFMA16(Af0.v, SL[2].v, zf); q1 = MFMA16(Af1.v, SL[3].v, q1); \
    f32x4 q2 = MFMA16(Af0.v, SL[4].v, zf); q2 = MFMA16(Af1.v, SL[5].v, q2); \
    f32x4 q3 = MFMA16(Af0.v, SL[6].v, zf); q3 = MFMA16(Af1.v, SL[7].v, q3); \
    float n0 = q0[0], n1 = q1[0], n2 = q2[0], n3 = q3[0]; \
    float mm = fmaxf(fmaxf(n0, n1), fmaxf(n2, n3)); \
    mm = fmaxf(mm, __shfl_xor(mm, 1, 64)); mm = fmaxf(mm, __shfl_xor(mm, 2, 64)); \
    mm = fmaxf(mm, __shfl_xor(mm, 4, 64)); mm = fmaxf(mm, __shfl_xor(mm, 8, 64)); \
    float inv = frcp(mm); C2 += LN2 * flog2(mm); \
    a0 = n0 * inv; a1 = n1 * inv; a2 = n2 * inv; a3 = n3 * inv; \
    if ((LD) >= 0) { MLOAD(SL, LD); } \
} while (0)

__global__ __launch_bounds__(128, 1)
void crf_comb_kernel(const float* __restrict__ u, const float* __restrict__ trans,
                     const unsigned* __restrict__ Mbuf, const float* __restrict__ Cseg,
                     float* __restrict__ out) {
    const int tid  = threadIdx.x;
    const int wid  = tid >> 6;           // 0 = front fold, 1 = back fold
    const int lane = tid & 63;
    const int col  = lane & 15;
    const int g    = lane >> 4;
    const int b    = blockIdx.x;
    const float K = 1.4426950408889634f, LN2 = 0.6931471805599453f;
    const f32x4 zf = {0.f, 0.f, 0.f, 0.f};

    __shared__ float sX[64], sY[64], sC[2];

    float a0, a1, a2, a3;
    if (wid == 0) {   // x = w0 = exp(u0 + tStart), row vector
        a0 = fexp2((u[(size_t)b*64 +  0 + col] + trans[( 0 + col)*64 + START_IDX]) * K);
        a1 = fexp2((u[(size_t)b*64 + 16 + col] + trans[(16 + col)*64 + START_IDX]) * K);
        a2 = fexp2((u[(size_t)b*64 + 32 + col] + trans[(32 + col)*64 + START_IDX]) * K);
        a3 = fexp2((u[(size_t)b*64 + 48 + col] + trans[(48 + col)*64 + START_IDX]) * K);
    } else {          // a = f = exp(tEnd), row vector
        a0 = fexp2(trans[END_IDX*64 +  0 + col] * K);
        a1 = fexp2(trans[END_IDX*64 + 16 + col] * K);
        a2 = fexp2(trans[END_IDX*64 + 32 + col] * K);
        a3 = fexp2(trans[END_IDX*64 + 48 + col] * K);
    }

    const int sbase = (lane & 48) | ((g & 1) << 3);
    const unsigned* mbase = Mbuf + (size_t)b * SEGS * 2048 + lane * 4;

    U8 MP0[8], MP1[8], MP2[8], MP3[8];
    float C2 = 0.0f;

    if (wid == 0) {
        MLOAD(MP0, 0); MLOAD(MP1, 1); MLOAD(MP2, 2); MLOAD(MP3, 3);
        PSTEP(24, MP0,  4); PSTEP(24, MP1,  5); PSTEP(24, MP2,  6); PSTEP(24, MP3,  7);
        PSTEP(24, MP0, -1); PSTEP(16, MP1, -1); PSTEP(8,  MP2, -1); PSTEP(0,  MP3, -1);
    } else {
        MLOAD(MP0, 15); MLOAD(MP1, 14); MLOAD(MP2, 13); MLOAD(MP3, 12);
        PSTEP(24, MP0, 11); PSTEP(24, MP1, 10); PSTEP(24, MP2,  9); PSTEP(24, MP3,  8);
        PSTEP(24, MP0, -1); PSTEP(16, MP1, -1); PSTEP(8,  MP2, -1); PSTEP(0,  MP3, -1);
    }

    if (g == 0) {
        float* dstv = wid ? sY : sX;
        dstv[ 0 + col] = a0; dstv[16 + col] = a1;
        dstv[32 + col] = a2; dstv[48 + col] = a3;
    }
    if (wid == 1) {
        float cs = (lane < SEGS) ? Cseg[b*SEGS + lane] : 0.0f;
#pragma unroll
        for (int m = 1; m < 64; m <<= 1) cs += __shfl_xor(cs, m, 64);
        if (lane == 0) sC[1] = C2 + cs;
    } else if (lane == 0) sC[0] = C2;
    __syncthreads();

    if (tid < 16) {
        float part = 0.0f;
#pragma unroll
        for (int cc = 0; cc < 4; ++cc)
            part = fmaf(sX[16*cc + tid], sY[16*cc + tid], part);
        part += __shfl_xor(part, 1, 64);
        part += __shfl_xor(part, 2, 64);
        part += __shfl_xor(part, 4, 64);
        part += __shfl_xor(part, 8, 64);
        if (tid == 0) out[b] = sC[0] + sC[1] + LN2 * flog2(part);
    }
}

// =========================================================================
// Fallback (ws too small): R6 fwd/bwd serial kernel, direct layout.
// =========================================================================
#define LOAD4O(RB, PTR) do { const float* _p = (PTR); \
    asm volatile("global_load_dwordx4 %0, %1, off"            : "=v"(RB[0].v) : "v"(_p)); \
    asm volatile("global_load_dwordx4 %0, %1, off offset:64"  : "=v"(RB[1].v) : "v"(_p)); \
    asm volatile("global_load_dwordx4 %0, %1, off offset:128" : "=v"(RB[2].v) : "v"(_p)); \
    asm volatile("global_load_dwordx4 %0, %1, off offset:192" : "=v"(RB[3].v) : "v"(_p)); \
} while (0)

template<bool EUP, bool RS, bool SNAPW>
__device__ __forceinline__ void stepfn(F4 (&D)[4], F4 (&UB)[4], const U8 (&A)[4][2],
                                       bool ccw, F4 (&wS)[4], float &snapC, float &C) {
    const float K = 1.4426950408889634f, LN2 = 0.6931471805599453f;
    const f32x4 zf = {0.f, 0.f, 0.f, 0.f};
    F4 W[4];
#pragma unroll
    for (int tt = 0; tt < 4; ++tt) {
        if (EUP) {
            W[tt].h[0] = pkmul(D[tt].h[0], UB[tt].h[0]);
            W[tt].h[1] = pkmul(D[tt].h[1], UB[tt].h[1]);
        } else {
#pragma unroll
            for (int r = 0; r < 4; ++r) W[tt].f[r] = D[tt].f[r] * fexp2(UB[tt].f[r] * K);
        }
    }
    if (RS) {
        float m0 = fmaxf(fmaxf(W[0].f[0], W[0].f[1]), fmaxf(W[0].f[2], W[0].f[3]));
        float m1 = fmaxf(fmaxf(W[1].f[0], W[1].f[1]), fmaxf(W[1].f[2], W[1].f[3]));
        float m2 = fmaxf(fmaxf(W[2].f[0], W[2].f[1]), fmaxf(W[2].f[2], W[2].f[3]));
        float m3 = fmaxf(fmaxf(W[3].f[0], W[3].f[1]), fmaxf(W[3].f[2], W[3].f[3]));
        float mm = fmaxf(fmaxf(m0, m1), fmaxf(m2, m3));
        mm = fmaxf(mm, __shfl_xor(mm, 16, 64));
        mm = fmaxf(mm, __shfl_xor(mm, 32, 64));
        float inv = frcp(mm);
        C += LN2 * flog2(mm);
        f32x2 iv; iv[0] = inv; iv[1] = inv;
#pragma unroll
        for (int tt = 0; tt < 4; ++tt) {
            W[tt].h[0] = pkmul(W[tt].h[0], iv);
            W[tt].h[1] = pkmul(W[tt].h[1], iv);
        }
    }
    if (SNAPW) {
        if (__ballot(ccw)) {
#pragma unroll
            for (int tt = 0; tt < 4; ++tt) {
#pragma unroll
                for (int r = 0; r < 4; ++r)
                    wS[tt].f[r] = ccw ? W[tt].f[r] : wS[tt].f[r];
            }
            snapC = ccw ? C : snapC;
        }
    }
    unsigned p00 = cvtpk(W[0].f[0], W[0].f[1]), p01 = cvtpk(W[0].f[2], W[0].f[3]);
    unsigned p10 = cvtpk(W[1].f[0], W[1].f[1]), p11 = cvtpk(W[1].f[2], W[1].f[3]);
    unsigned p20 = cvtpk(W[2].f[0], W[2].f[1]), p21 = cvtpk(W[2].f[2], W[2].f[3]);
    unsigned p30 = cvtpk(W[3].f[0], W[3].f[1]), p31 = cvtpk(W[3].f[2], W[3].f[3]);
    swap32(p00, p10); swap32(p01, p11); swap32(p20, p30); swap32(p21, p31);
    swap16(p00, p10); swap16(p01, p11); swap16(p20, p30); swap16(p21, p31);
    U8 b0, b1;
    b0.u[0] = p00; b0.u[1] = p01; b0.u[2] = p10; b0.u[3] = p11;
    b1.u[0] = p20; b1.u[1] = p21; b1.u[2] = p30; b1.u[3] = p31;
#pragma unroll
    for (int tt = 0; tt < 4; ++tt) {
        f32x4 acc = MFMA16(A[tt][0].v, b0.v, zf);
        D[tt].v   = MFMA16(A[tt][1].v, b1.v, acc);
    }
}

__device__ __forceinline__ void make_frags(const float* sT, int wid, int col, int g,
                                           U8 (&A)[4][2], F4 (&D)[4]) {
    const float K = 1.4426950408889634f;
    if (wid == 0) {
#pragma unroll
        for (int tt = 0; tt < 4; ++tt) {
#pragma unroll
            for (int c = 0; c < 2; ++c) {
                const float* p = &sT[(16*tt + col)*64 + 32*c + 8*g];
#pragma unroll
                for (int j2 = 0; j2 < 4; ++j2)
                    A[tt][c].u[j2] = cvtpk(fexp2(p[2*j2]*K), fexp2(p[2*j2+1]*K));
            }
        }
#pragma unroll
        for (int tt = 0; tt < 4; ++tt) {
#pragma unroll
            for (int r = 0; r < 4; ++r)
                D[tt].f[r] = fexp2(sT[(16*tt + 4*g + r)*64 + START_IDX] * K);
        }
    } else {
#pragma unroll
        for (int tt = 0; tt < 4; ++tt) {
#pragma unroll
            for (int c = 0; c < 2; ++c) {
#pragma unroll
                for (int j2 = 0; j2 < 4; ++j2) {
                    const int a0 = 32*c + 8*g + 2*j2;
                    A[tt][c].u[j2] = cvtpk(fexp2(sT[a0*64 + 16*tt + col] * K),
                                           fexp2(sT[(a0+1)*64 + 16*tt + col] * K));
                }
            }
        }
#pragma unroll
        for (int tt = 0; tt < 4; ++tt) {
#pragma unroll
            for (int r = 0; r < 4; ++r)
                D[tt].f[r] = fexp2(sT[END_IDX*64 + 16*tt + 4*g + r] * K);
        }
    }
}

__launch_bounds__(128, 1)
__global__ void crf_fb_old(const float* __restrict__ src,
                           const float* __restrict__ trans,
                           const int* __restrict__ lengths,
                           float* __restrict__ out) {
    const int tid  = threadIdx.x;
    const int wid  = tid >> 6;
    const int lane = tid & 63;
    const int col  = lane & 15;
    const int g    = lane >> 4;
    const int bidx = blockIdx.x * 16 + col;

    __shared__ __align__(16) float sT[N_TAGS * N_TAGS];
    __shared__ __align__(16) float sW[N_TAGS * 16];
    __shared__ __align__(16) float sV[N_TAGS * 16];
    __shared__ float sCf[16], sCb[16];

    {
        const float4* t4 = (const float4*)trans;
        float4* s4 = (float4*)sT;
#pragma unroll
        for (int k2 = 0; k2 < 8; ++k2) s4[k2 * 128 + tid] = t4[k2 * 128 + tid];
    }
    __syncthreads();

    const float LN2 = 0.6931471805599453f;
    const int len = lengths[bidx];
    const int M   = (len - 1) >> 1;
    const int Kb  = (len - 1) - M;

    U8 A[4][2];
    F4 D[4];
    make_frags(sT, wid, col, g, A, D);

    int need = (wid == 0) ? (M + 1) : Kb;
    int mx = need;
#pragma unroll
    for (int m = 1; m < 64; m <<= 1) mx = max(mx, __shfl_xor(mx, m, 64));
    mx = __builtin_amdgcn_readfirstlane(mx);

    const int base = bidx * 64 + 4 * g;
    float C = 0.0f, snapC = 0.0f;
    F4 wS[4];
#pragma unroll
    for (int tt = 0; tt < 4; ++tt) wS[tt] = D[tt];

    F4 R0[4], R1[4], R2[4], R3[4], R4_[4], R5[4], R6[4], R7[4];

    if (wid == 0) {
        const float* pf = src + base;
        LOAD4O(R0, pf);            LOAD4O(R1, pf + BN_);
        LOAD4O(R2, pf + 2*BN_);    LOAD4O(R3, pf + 3*BN_);
        LOAD4O(R4_, pf + 4*BN_);   LOAD4O(R5, pf + 5*BN_);
        LOAD4O(R6, pf + 6*BN_);    LOAD4O(R7, pf + 7*BN_);
        const float* pn = pf + 8 * BN_;
        const int Nf = (mx + 7) & ~7;
        for (int s = 0; s < Nf; s += 8) {
#define FSTEP(QQ, RB, RSF) do { \
            const int t_ = s + (QQ); \
            wait28(); \
            stepfn<false, RSF, true>(D, RB, A, (t_ == M), wS, snapC, C); \
            LOAD4O(RB, pn); pn += BN_; \
        } while (0)
            FSTEP(0, R0, false); FSTEP(1, R1, false); FSTEP(2, R2, false);
            FSTEP(3, R3, false); FSTEP(4, R4_, false); FSTEP(5, R5, false);
            FSTEP(6, R6, false); FSTEP(7, R7, true);
#undef FSTEP
        }
        wait0();
    } else {
        const float* pb = src + base;
        {
#define PRIME(RB, q) do { int tq = max(len - 1 - (q), 0); LOAD4O(RB, pb + tq * BN_); } while (0)
            PRIME(R0, 0); PRIME(R1, 1); PRIME(R2, 2); PRIME(R3, 3);
            PRIME(R4_, 4); PRIME(R5, 5); PRIME(R6, 6); PRIME(R7, 7);
#undef PRIME
        }
        int tP = len - 9;
        const int Nb = (mx + 7) & ~7;
        for (int s = 0; s < Nb; s += 8) {
#define BSTEP(QQ, RB, RSF) do { \
            const int k_ = s + (QQ) + 1; \
            wait28(); \
            stepfn<false, RSF, false>(D, RB, A, false, wS, snapC, C); \
            if (__ballot(k_ == Kb)) { \
                const bool cc = (k_ == Kb); \
                _Pragma("unroll") \
                for (int tt = 0; tt < 4; ++tt) { \
                    _Pragma("unroll") \
                    for (int r = 0; r < 4; ++r) \
                        wS[tt].f[r] = cc ? D[tt].f[r] : wS[tt].f[r]; \
                } \
                snapC = cc ? C : snapC; \
            } \
            int tc = max(tP, 0); LOAD4O(RB, pb + tc * BN_); tP -= 1; \
        } while (0)
            BSTEP(0, R0, false); BSTEP(1, R1, false); BSTEP(2, R2, false);
            BSTEP(3, R3, false); BSTEP(4, R4_, false); BSTEP(5, R5, false);
            BSTEP(6, R6, false); BSTEP(7, R7, true);
#undef BSTEP
        }
        wait0();
    }

    {
        float* dstv = (wid == 0) ? sW : sV;
#pragma unroll
        for (int tt = 0; tt < 4; ++tt) {
#pragma unroll
            for (int r = 0; r < 4; ++r)
                dstv[(16*tt + 4*g + r) * 16 + col] = wS[tt].f[r];
        }
        if (g == 0) { if (wid == 0) sCf[col] = snapC; else sCb[col] = snapC; }
    }
    __syncthreads();
    if (wid == 0) {
        float part = 0.0f;
#pragma unroll
        for (int j = 0; j < 16; ++j) {
            const int n = g * 16 + j;
            part = fmaf(sW[n * 16 + col], sV[n * 16 + col], part);
        }
        part += __shfl_xor(part, 16, 64);
        part += __shfl_xor(part, 32, 64);
        if (g == 0) out[bidx] = sCf[col] + sCb[col] + LN2 * flog2(part);
    }
}

extern "C" void kernel_launch(void* const* d_in, const int* in_sizes, int n_in,
                              void* d_out, int out_size, void* d_ws, size_t ws_size,
                              hipStream_t stream) {
    const float* unary   = (const float*)d_in[0];
    const float* trans   = (const float*)d_in[1];
    const int*   lengths = (const int*)d_in[2];
    float* out = (float*)d_out;

    const size_t mcount = (size_t)B_SIZE * SEGS * 2048;       // u32 elements
    const size_t need   = mcount * 4 + (size_t)B_SIZE * SEGS * 4;
    if (ws_size >= need) {
        unsigned* Mbuf = (unsigned*)d_ws;
        float* Cseg = (float*)((unsigned*)d_ws + mcount);
        hipLaunchKernelGGL(crf_seg_kernel, dim3(B_SIZE * SEGS), dim3(64), 0, stream,
                           unary, trans, lengths, Mbuf, Cseg);
        hipLaunchKernelGGL(crf_comb_kernel, dim3(B_SIZE), dim3(128), 0, stream,
                           unary, trans, Mbuf, Cseg, out);
    } else {
        hipLaunchKernelGGL(crf_fb_old, dim3(B_SIZE / 16), dim3(128), 0, stream,
                           unary, trans, lengths, out);
    }
}